// Round 10
// baseline (217.970 us; speedup 1.0000x reference)
//
#include <hip/hip_runtime.h>
#include <hip/hip_bf16.h>

// GIN 2-layer, bf16 feature pipeline + MFMA MLPs.
// r10: bhist fused into prep (hides behind weight/x conversion);
// p1 flush rewritten as 16-lane coalesced per-bucket run copies.

#define CB   512        // nodes per coarse bucket
#define NBMX 256        // max buckets (bucket path requires nbuck <= 256)
#define CAP  48         // LDS staged entries per bucket (p1)
#define FL   16         // flush granularity (16 x u32 = 64 B line)

typedef short  bf16x8 __attribute__((ext_vector_type(8)));
typedef float  f32x4  __attribute__((ext_vector_type(4)));

__device__ inline float bf2f(unsigned short u) {
    unsigned int t = ((unsigned int)u) << 16;
    return __builtin_bit_cast(float, t);
}
__device__ inline unsigned short f2bf(float f) {   // round-to-nearest-even
    unsigned int u = __builtin_bit_cast(unsigned int, f);
    u += 0x7fffu + ((u >> 16) & 1u);
    return (unsigned short)(u >> 16);
}

// ------- fused prep: [0,64) bucket-hist | [64,256) weights | rest x->bf16 ----
__global__ __launch_bounds__(256) void prep_k(
    const float* __restrict__ x, unsigned short* __restrict__ xb, int n8,
    const float* __restrict__ W1a, const float* __restrict__ W1b,
    const float* __restrict__ W2a, const float* __restrict__ W2b,
    unsigned short* __restrict__ T1a, unsigned short* __restrict__ T1b,
    unsigned short* __restrict__ T2a, unsigned short* __restrict__ T2b,
    const int* __restrict__ dst, int* __restrict__ bcnt,
    int hist_edges, int nbuck)
{
    __shared__ int lh[NBMX];
    const int b = blockIdx.x;
    const int tid = threadIdx.x;
    if (b < 64) {                        // bucket histogram role
        if (hist_edges == 0) return;
        for (int i = tid; i < nbuck; i += 256) lh[i] = 0;
        __syncthreads();
        const int e4 = hist_edges >> 2;
        const int stride = 64 * 256;
        for (int i4 = b * 256 + tid; i4 < e4; i4 += stride) {
            int4 dv = reinterpret_cast<const int4*>(dst)[i4];
            atomicAdd(&lh[dv.x / CB], 1);
            atomicAdd(&lh[dv.y / CB], 1);
            atomicAdd(&lh[dv.z / CB], 1);
            atomicAdd(&lh[dv.w / CB], 1);
        }
        if (b == 0 && tid < (hist_edges & 3))
            atomicAdd(&lh[dst[e4 * 4 + tid] / CB], 1);
        __syncthreads();
        for (int i = tid; i < nbuck; i += 256) {
            int v = lh[i];
            if (v) atomicAdd(&bcnt[i], v);
        }
    } else if (b < 256) {                // weight transpose role
        int idx = (b - 64) * 256 + tid;
        const float* W; unsigned short* T; int K, N;
        if (idx < 8192)        { W = W1a; T = T1a; K = 64;  N = 128; }
        else if (idx < 24576)  { idx -= 8192;  W = W1b; T = T1b; K = 128; N = 128; }
        else if (idx < 40960)  { idx -= 24576; W = W2a; T = T2a; K = 128; N = 128; }
        else if (idx < 49152)  { idx -= 40960; W = W2b; T = T2b; K = 128; N = 64; }
        else return;
        int n = idx / K, k = idx - n * K;
        T[idx] = f2bf(W[(size_t)k * N + n]);
    } else {                             // x -> bf16 role
        int i = (b - 256) * 256 + tid;
        if (i >= n8) return;
        const float4* p = reinterpret_cast<const float4*>(x + (size_t)i * 8);
        float4 a = p[0], c = p[1];
        union { unsigned short us[8]; uint4 v; } o;
        o.us[0] = f2bf(a.x); o.us[1] = f2bf(a.y); o.us[2] = f2bf(a.z); o.us[3] = f2bf(a.w);
        o.us[4] = f2bf(c.x); o.us[5] = f2bf(c.y); o.us[6] = f2bf(c.z); o.us[7] = f2bf(c.w);
        *reinterpret_cast<uint4*>(xb + (size_t)i * 8) = o.v;
    }
}

// ---------------- bucket scan (1 block): boffs + gcur ----------------
__global__ __launch_bounds__(256) void bscan_k(
    const int* __restrict__ bcnt, int* __restrict__ boffs,
    int* __restrict__ gcur, int nbuck)
{
    __shared__ int s[256];
    const int tid = threadIdx.x;
    int v = (tid < nbuck) ? bcnt[tid] : 0;
    s[tid] = v; __syncthreads();
    #pragma unroll
    for (int d = 1; d < 256; d <<= 1) {
        int t = (tid >= d) ? s[tid - d] : 0;
        __syncthreads();
        s[tid] += t;
        __syncthreads();
    }
    if (tid < nbuck) {
        int excl = s[tid] - v;
        boffs[tid] = excl;
        gcur[tid] = excl;
        if (tid == nbuck - 1) boffs[nbuck] = s[tid];
    }
}

// ---------------- pass 1: LDS-staged binning, coalesced flush ----------------
template<bool VEC4>
__global__ __launch_bounds__(256) void bucket_p1_k(
    const int* __restrict__ src, const int* __restrict__ dst,
    int* __restrict__ gcur, unsigned int* __restrict__ tmp,
    int n_edges, int nb)
{
    __shared__ unsigned int stage[NBMX][CAP];
    __shared__ int scnt[NBMX];
    __shared__ int fbase[NBMX];
    __shared__ short fcnt[NBMX];
    __shared__ short foff[NBMX];
    const int tid = threadIdx.x;
    for (int b = tid; b < nb; b += 256) scnt[b] = 0;
    __syncthreads();

    const int e4total = n_edges >> 2;
    const int stride = gridDim.x * 256;
    const int iters = (e4total + stride - 1) / stride;

    for (int it = 0; it < iters; ++it) {
        int i4 = it * stride + blockIdx.x * 256 + tid;
        if (i4 < e4total) {
            int s4[4], d4[4];
            if constexpr (VEC4) {
                int4 sv = reinterpret_cast<const int4*>(src)[i4];
                int4 dv = reinterpret_cast<const int4*>(dst)[i4];
                s4[0]=sv.x; s4[1]=sv.y; s4[2]=sv.z; s4[3]=sv.w;
                d4[0]=dv.x; d4[1]=dv.y; d4[2]=dv.z; d4[3]=dv.w;
            } else {
                #pragma unroll
                for (int j = 0; j < 4; ++j) { s4[j]=src[i4*4+j]; d4[j]=dst[i4*4+j]; }
            }
            #pragma unroll
            for (int j = 0; j < 4; ++j) {
                int dd = d4[j];
                int b = dd / CB;
                unsigned int entry = (unsigned int)s4[j] | ((unsigned int)(dd - b * CB) << 20);
                int slot = atomicAdd(&scnt[b], 1);
                if (slot < CAP) stage[b][slot] = entry;
                else { int p = atomicAdd(&gcur[b], 1); tmp[p] = entry; }
            }
        }
        __syncthreads();
        // flush bookkeeping: thread b owns bucket b
        if (tid < nb) {
            int m = scnt[tid]; if (m > CAP) m = CAP;
            int nf = m & ~(FL - 1);
            fcnt[tid] = (short)nf;
            foff[tid] = (short)(m - nf);         // flush TOP [m-nf, m)
            fbase[tid] = nf ? atomicAdd(&gcur[tid], nf) : 0;
            scnt[tid] = m - nf;                  // leftover stays at bottom
        }
        __syncthreads();
        // coalesced copy: 16 lanes per bucket -> 64 B line per 16-run
        for (int bb = tid >> 4; bb < nb; bb += 16) {
            int q = tid & 15;
            int nf = fcnt[bb];
            if (nf) {
                int off = foff[bb], base = fbase[bb];
                for (int u = q; u < nf; u += 16)
                    tmp[base + u] = stage[bb][off + u];
            }
        }
        __syncthreads();
    }
    // drain leftovers (< FL per bucket)
    if (tid < nb) {
        int m = scnt[tid]; if (m > CAP) m = CAP;
        if (m > 0) {
            int base = atomicAdd(&gcur[tid], m);
            for (int q = 0; q < m; ++q) tmp[base + q] = stage[tid][q];
        }
    }
    // scalar tail (n_edges % 4)
    if (blockIdx.x == 0 && tid < (n_edges & 3)) {
        int e = e4total * 4 + tid;
        int dd = dst[e];
        int b = dd / CB;
        unsigned int entry = (unsigned int)src[e] | ((unsigned int)(dd - b * CB) << 20);
        int p = atomicAdd(&gcur[b], 1);
        tmp[p] = entry;
    }
}

// ---------------- pass 2: bucket-local count + scan + scatter (proven) -------
__global__ __launch_bounds__(256) void bucket_csr_k(
    const unsigned int* __restrict__ tmp, const int* __restrict__ boffs,
    int* __restrict__ offs, int* __restrict__ cnt, int* __restrict__ eidx,
    int n_nodes)
{
    __shared__ int lcnt[CB];
    __shared__ int lcur[CB];
    __shared__ int ssum[256];
    const int b = blockIdx.x;
    const int tid = threadIdx.x;
    const int node0 = b * CB;
    const int nn = min(CB, n_nodes - node0);
    const int lo = boffs[b], hi = boffs[b + 1];

    for (int i = tid; i < CB; i += 256) lcnt[i] = 0;
    __syncthreads();
    for (int i = lo + tid; i < hi; i += 256)
        atomicAdd(&lcnt[tmp[i] >> 20], 1);
    __syncthreads();

    int a0 = lcnt[tid * 2], a1 = lcnt[tid * 2 + 1];
    int tsum = a0 + a1;
    ssum[tid] = tsum; __syncthreads();
    #pragma unroll
    for (int d = 1; d < 256; d <<= 1) {
        int t = (tid >= d) ? ssum[tid - d] : 0;
        __syncthreads();
        ssum[tid] += t;
        __syncthreads();
    }
    int run = ssum[tid] - tsum;

    lcur[tid * 2]     = run;
    lcur[tid * 2 + 1] = run + a0;
    int g0 = node0 + tid * 2;
    if (tid * 2 < nn)     { offs[g0]     = lo + run;      cnt[g0]     = a0; }
    if (tid * 2 + 1 < nn) { offs[g0 + 1] = lo + run + a0; cnt[g0 + 1] = a1; }
    __syncthreads();

    for (int i = lo + tid; i < hi; i += 256) {
        unsigned int v = tmp[i];
        int p = atomicAdd(&lcur[v >> 20], 1);
        eidx[lo + p] = (int)(v & 0xFFFFFu);
    }
}

// ---------------- fallback pipeline (nbuck > NBMX) ----------------
__global__ __launch_bounds__(256) void hist_k(
    const int* __restrict__ dst, int* __restrict__ cnt, int n_edges)
{
    int e = blockIdx.x * 256 + threadIdx.x;
    if (e < n_edges) atomicAdd(&cnt[dst[e]], 1);
}

__global__ __launch_bounds__(256) void scan_block_k(
    const int* __restrict__ cnt, int* __restrict__ offs, int* __restrict__ bsum, int n)
{
    __shared__ int s[256];
    const int tid = threadIdx.x;
    const int base = blockIdx.x * 2048 + tid * 8;
    int v[8]; int tsum = 0;
    #pragma unroll
    for (int j = 0; j < 8; ++j) {
        int idx = base + j;
        v[j] = (idx < n) ? cnt[idx] : 0;
        tsum += v[j];
    }
    s[tid] = tsum; __syncthreads();
    #pragma unroll
    for (int d = 1; d < 256; d <<= 1) {
        int t = (tid >= d) ? s[tid - d] : 0;
        __syncthreads();
        s[tid] += t;
        __syncthreads();
    }
    int run = s[tid] - tsum;
    #pragma unroll
    for (int j = 0; j < 8; ++j) {
        int idx = base + j;
        if (idx < n) offs[idx] = run;
        run += v[j];
    }
    if (tid == 255) bsum[blockIdx.x] = s[255];
}

__global__ __launch_bounds__(256) void scan_bsum_k(int* __restrict__ bsum, int nb)
{
    __shared__ int s[256];
    const int tid = threadIdx.x;
    int v = (tid < nb) ? bsum[tid] : 0;
    s[tid] = v; __syncthreads();
    #pragma unroll
    for (int d = 1; d < 256; d <<= 1) {
        int t = (tid >= d) ? s[tid - d] : 0;
        __syncthreads();
        s[tid] += t;
        __syncthreads();
    }
    if (tid < nb) bsum[tid] = s[tid] - v;
}

__global__ __launch_bounds__(256) void scan_add_k(
    int* __restrict__ offs, int* __restrict__ cur, const int* __restrict__ bsum, int n)
{
    const int b = bsum[blockIdx.x];
    const int base = blockIdx.x * 2048 + threadIdx.x * 8;
    #pragma unroll
    for (int j = 0; j < 8; ++j) {
        int idx = base + j;
        if (idx < n) { int o = offs[idx] + b; offs[idx] = o; cur[idx] = o; }
    }
}

__global__ __launch_bounds__(256) void fill_k(
    const int* __restrict__ src, const int* __restrict__ dst,
    int* __restrict__ cur, int* __restrict__ eidx, int n_edges)
{
    int e = blockIdx.x * 256 + threadIdx.x;
    if (e < n_edges) {
        int p = atomicAdd(&cur[dst[e]], 1);
        eidx[p] = src[e];
    }
}

// ---------------- gather aggregation: A = self + sum(nbrs), 4-edge unroll ----
template<int C>
__global__ __launch_bounds__(256) void gather_agg_k(
    const unsigned short* __restrict__ h, const int* __restrict__ offs,
    const int* __restrict__ cnt, const int* __restrict__ eidx,
    unsigned short* __restrict__ A, int n_nodes)
{
    constexpr int TPN = C / 8;
    constexpr int NPB = 256 / TPN;
    const int node = blockIdx.x * NPB + threadIdx.x / TPN;
    const int lane = threadIdx.x % TPN;
    if (node >= n_nodes) return;
    const size_t coff = (size_t)lane * 8;

    float acc[8];
    {
        uint4 v = *reinterpret_cast<const uint4*>(h + (size_t)node * C + coff);
        const unsigned short* u = (const unsigned short*)&v;
        #pragma unroll
        for (int j = 0; j < 8; ++j) acc[j] = bf2f(u[j]);
    }
    const int beg = offs[node], end = beg + cnt[node];
    int p = beg;
    for (; p + 4 <= end; p += 4) {
        int s0 = eidx[p], s1 = eidx[p + 1], s2 = eidx[p + 2], s3 = eidx[p + 3];
        uint4 v0 = *reinterpret_cast<const uint4*>(h + (size_t)s0 * C + coff);
        uint4 v1 = *reinterpret_cast<const uint4*>(h + (size_t)s1 * C + coff);
        uint4 v2 = *reinterpret_cast<const uint4*>(h + (size_t)s2 * C + coff);
        uint4 v3 = *reinterpret_cast<const uint4*>(h + (size_t)s3 * C + coff);
        const unsigned short* u0 = (const unsigned short*)&v0;
        const unsigned short* u1 = (const unsigned short*)&v1;
        const unsigned short* u2 = (const unsigned short*)&v2;
        const unsigned short* u3 = (const unsigned short*)&v3;
        #pragma unroll
        for (int j = 0; j < 8; ++j)
            acc[j] += (bf2f(u0[j]) + bf2f(u1[j])) + (bf2f(u2[j]) + bf2f(u3[j]));
    }
    if (p + 2 <= end) {
        int s0 = eidx[p], s1 = eidx[p + 1];
        uint4 v0 = *reinterpret_cast<const uint4*>(h + (size_t)s0 * C + coff);
        uint4 v1 = *reinterpret_cast<const uint4*>(h + (size_t)s1 * C + coff);
        const unsigned short* u0 = (const unsigned short*)&v0;
        const unsigned short* u1 = (const unsigned short*)&v1;
        #pragma unroll
        for (int j = 0; j < 8; ++j) acc[j] += bf2f(u0[j]) + bf2f(u1[j]);
        p += 2;
    }
    if (p < end) {
        uint4 v0 = *reinterpret_cast<const uint4*>(h + (size_t)eidx[p] * C + coff);
        const unsigned short* u0 = (const unsigned short*)&v0;
        #pragma unroll
        for (int j = 0; j < 8; ++j) acc[j] += bf2f(u0[j]);
    }
    union { unsigned short us[8]; uint4 v; } o;
    #pragma unroll
    for (int j = 0; j < 8; ++j) o.us[j] = f2bf(acc[j]);
    *reinterpret_cast<uint4*>(A + (size_t)node * C + coff) = o.v;
}

// ---------------- fused 2-GEMM MLP via MFMA bf16, 128-row tile (proven r9) ---
template<int K1, int N2, bool RELU_OUT, bool OUT_BF16>
__global__ __launch_bounds__(256) void mlp_mfma_k(
    const unsigned short* __restrict__ Ain,
    const unsigned short* __restrict__ WTa,
    const float* __restrict__ ba,
    const unsigned short* __restrict__ WTb,
    const float* __restrict__ bb,
    void* __restrict__ outp, int n_nodes)
{
    constexpr int KS1 = K1 / 32;
    constexpr int NT2 = N2 / 16;
    static_assert(128 * K1 <= 128 * 128, "sA fits sAM");
    static_assert(128 * N2 * (OUT_BF16 ? 2 : 4) <= 128 * 128 * 2, "out stage fits sAM");

    __shared__ __align__(16) unsigned short sAM[128 * 128];  // sA / sMid / out
    __shared__ __align__(16) unsigned short sWa[128 * K1];
    __shared__ __align__(16) unsigned short sWb[N2 * 128];

    const int tid = threadIdx.x;
    const int wave = tid >> 6, lane = tid & 63;
    const int rc = lane & 15;
    const int kg = lane >> 4;
    const int rowBlock = blockIdx.x * 128;

    {   // stage A [128][K1] (guarded rows), swizzled
        constexpr int CPR = K1 / 8;
        #pragma unroll
        for (int f = tid; f < 128 * CPR; f += 256) {
            int r = f / CPR, c = f - r * CPR;
            uint4 v = make_uint4(0u, 0u, 0u, 0u);
            int gr = rowBlock + r;
            if (gr < n_nodes)
                v = *reinterpret_cast<const uint4*>(Ain + (size_t)gr * K1 + c * 8);
            int byte = r * (K1 * 2) + ((c * 16) ^ ((r & 7) << 4));
            *reinterpret_cast<uint4*>((char*)sAM + byte) = v;
        }
    }
    {   // stage WTa [128][K1], swizzled
        constexpr int CPR = K1 / 8;
        #pragma unroll
        for (int f = tid; f < 128 * CPR; f += 256) {
            int r = f / CPR, c = f - r * CPR;
            uint4 v = *reinterpret_cast<const uint4*>(WTa + (size_t)r * K1 + c * 8);
            int byte = r * (K1 * 2) + ((c * 16) ^ ((r & 7) << 4));
            *reinterpret_cast<uint4*>((char*)sWa + byte) = v;
        }
    }
    {   // stage WTb [N2][128], swizzled
        #pragma unroll
        for (int f = tid; f < N2 * 16; f += 256) {
            int r = f / 16, c = f - r * 16;
            uint4 v = *reinterpret_cast<const uint4*>(WTb + (size_t)r * 128 + c * 8);
            int byte = r * 256 + ((c * 16) ^ ((r & 7) << 4));
            *reinterpret_cast<uint4*>((char*)sWb + byte) = v;
        }
    }
    __syncthreads();

    // ---- GEMM1: (128 x K1) @ (K1 x 128) ----
    bf16x8 af[2][KS1];
    #pragma unroll
    for (int rt = 0; rt < 2; ++rt)
        #pragma unroll
        for (int ks = 0; ks < KS1; ++ks) {
            int r = wave * 32 + rt * 16 + rc;
            int byte = r * (K1 * 2) + (((ks * 32 + kg * 8) * 2) ^ ((r & 7) << 4));
            af[rt][ks] = *reinterpret_cast<const bf16x8*>((const char*)sAM + byte);
        }
    __syncthreads();   // all sA reads complete before sMid overwrite

    f32x4 acc1[2][8];
    #pragma unroll
    for (int rt = 0; rt < 2; ++rt)
        #pragma unroll
        for (int n = 0; n < 8; ++n) acc1[rt][n] = (f32x4){0.f, 0.f, 0.f, 0.f};
    #pragma unroll
    for (int n = 0; n < 8; ++n) {
        int c = n * 16 + rc;
        #pragma unroll
        for (int ks = 0; ks < KS1; ++ks) {
            int byte = c * (K1 * 2) + (((ks * 32 + kg * 8) * 2) ^ ((c & 7) << 4));
            bf16x8 bfr = *reinterpret_cast<const bf16x8*>((const char*)sWa + byte);
            #pragma unroll
            for (int rt = 0; rt < 2; ++rt)
                acc1[rt][n] = __builtin_amdgcn_mfma_f32_16x16x32_bf16(
                    af[rt][ks], bfr, acc1[rt][n], 0, 0, 0);
        }
    }
    // epilogue 1: bias + relu -> sMid (= sAM) bf16 [128][128] swizzled
    #pragma unroll
    for (int n = 0; n < 8; ++n) {
        int c = n * 16 + rc;
        float bias = ba[c];
        #pragma unroll
        for (int rt = 0; rt < 2; ++rt)
            #pragma unroll
            for (int i = 0; i < 4; ++i) {
                int r = wave * 32 + rt * 16 + kg * 4 + i;
                float v = fmaxf(acc1[rt][n][i] + bias, 0.f);
                int byte = r * 256 + ((c * 2) ^ ((r & 7) << 4));
                *reinterpret_cast<unsigned short*>((char*)sAM + byte) = f2bf(v);
            }
    }
    __syncthreads();

    // ---- GEMM2: (128 x 128) @ (128 x N2) ----
    bf16x8 mf[2][4];
    #pragma unroll
    for (int rt = 0; rt < 2; ++rt)
        #pragma unroll
        for (int ks = 0; ks < 4; ++ks) {
            int r = wave * 32 + rt * 16 + rc;
            int byte = r * 256 + (((ks * 32 + kg * 8) * 2) ^ ((r & 7) << 4));
            mf[rt][ks] = *reinterpret_cast<const bf16x8*>((const char*)sAM + byte);
        }
    f32x4 acc2[2][NT2];
    #pragma unroll
    for (int rt = 0; rt < 2; ++rt)
        #pragma unroll
        for (int n = 0; n < NT2; ++n) acc2[rt][n] = (f32x4){0.f, 0.f, 0.f, 0.f};
    #pragma unroll
    for (int n = 0; n < NT2; ++n) {
        int c = n * 16 + rc;
        #pragma unroll
        for (int ks = 0; ks < 4; ++ks) {
            int byte = c * 256 + (((ks * 32 + kg * 8) * 2) ^ ((c & 7) << 4));
            bf16x8 bfr = *reinterpret_cast<const bf16x8*>((const char*)sWb + byte);
            #pragma unroll
            for (int rt = 0; rt < 2; ++rt)
                acc2[rt][n] = __builtin_amdgcn_mfma_f32_16x16x32_bf16(
                    mf[rt][ks], bfr, acc2[rt][n], 0, 0, 0);
        }
    }
    __syncthreads();   // all sMid reads done before out-staging overwrite

    // ---- epilogue 2: bias [+relu] -> stage in sAM -> coalesced store ----
    if constexpr (OUT_BF16) {
        #pragma unroll
        for (int n = 0; n < NT2; ++n) {
            int c = n * 16 + rc;
            float bias = bb[c];
            #pragma unroll
            for (int rt = 0; rt < 2; ++rt)
                #pragma unroll
                for (int i = 0; i < 4; ++i) {
                    int r = wave * 32 + rt * 16 + kg * 4 + i;
                    float v = acc2[rt][n][i] + bias;
                    if (RELU_OUT) v = fmaxf(v, 0.f);
                    sAM[r * N2 + c] = f2bf(v);
                }
        }
        __syncthreads();
        unsigned short* out = (unsigned short*)outp;
        constexpr int CPR = N2 / 8;
        #pragma unroll
        for (int f = tid; f < 128 * CPR; f += 256) {
            int r = f / CPR, c = f - r * CPR;
            int gr = rowBlock + r;
            if (gr < n_nodes)
                *reinterpret_cast<uint4*>(out + (size_t)gr * N2 + c * 8) =
                    *reinterpret_cast<const uint4*>(sAM + r * N2 + c * 8);
        }
    } else {
        float* sOut = reinterpret_cast<float*>(sAM);   // [128][N2] f32
        #pragma unroll
        for (int n = 0; n < NT2; ++n) {
            int c = n * 16 + rc;
            float bias = bb[c];
            #pragma unroll
            for (int rt = 0; rt < 2; ++rt)
                #pragma unroll
                for (int i = 0; i < 4; ++i) {
                    int r = wave * 32 + rt * 16 + kg * 4 + i;
                    float v = acc2[rt][n][i] + bias;
                    if (RELU_OUT) v = fmaxf(v, 0.f);
                    sOut[r * N2 + c] = v;
                }
        }
        __syncthreads();
        float* out = (float*)outp;
        constexpr int CPR = N2 / 4;
        #pragma unroll
        for (int f = tid; f < 128 * CPR; f += 256) {
            int r = f / CPR, c = f - r * CPR;
            int gr = rowBlock + r;
            if (gr < n_nodes)
                *reinterpret_cast<float4*>(out + (size_t)gr * N2 + c * 4) =
                    *reinterpret_cast<const float4*>(sOut + r * N2 + c * 4);
        }
    }
}

extern "C" void kernel_launch(void* const* d_in, const int* in_sizes, int n_in,
                              void* d_out, int out_size, void* d_ws, size_t ws_size,
                              hipStream_t stream)
{
    const float* x   = (const float*)d_in[0];
    const int*   ei  = (const int*)d_in[1];
    const float* W1a = (const float*)d_in[2];
    const float* b1a = (const float*)d_in[3];
    const float* W1b = (const float*)d_in[4];
    const float* b1b = (const float*)d_in[5];
    const float* W2a = (const float*)d_in[6];
    const float* b2a = (const float*)d_in[7];
    const float* W2b = (const float*)d_in[8];
    const float* b2b = (const float*)d_in[9];

    const int n_nodes = in_sizes[0] / 64;
    const int n_edges = in_sizes[1] / 2;
    const int* src = ei;
    const int* dst = ei + n_edges;

    char* ws = (char*)d_ws;
    size_t o = 0;
    auto alloc = [&](size_t bytes) -> char* {
        char* p = ws + o;
        o += (bytes + 255) & ~(size_t)255;
        return p;
    };
    unsigned short* A    = (unsigned short*)alloc((size_t)n_nodes * 128 * 2);
    unsigned short* h    = (unsigned short*)alloc((size_t)n_nodes * 128 * 2);
    unsigned short* xb   = (unsigned short*)alloc((size_t)n_nodes * 64 * 2);
    int* eidx = (int*)alloc((size_t)n_edges * 4);
    unsigned int* tmp = (unsigned int*)alloc((size_t)n_edges * 4);
    int* cnt  = (int*)alloc((size_t)n_nodes * 4);
    int* offs = (int*)alloc((size_t)n_nodes * 4);
    int* cur  = (int*)alloc((size_t)n_nodes * 4);
    int* bsum = (int*)alloc(256 * 4);
    int* gcur = (int*)alloc(NBMX * 4);
    int* bcnt = (int*)alloc((NBMX + 1) * 4);
    int* boffs = (int*)alloc((NBMX + 1) * 4);
    unsigned short* WT1a = (unsigned short*)alloc(64 * 128 * 2);
    unsigned short* WT1b = (unsigned short*)alloc(128 * 128 * 2);
    unsigned short* WT2a = (unsigned short*)alloc(128 * 128 * 2);
    unsigned short* WT2b = (unsigned short*)alloc(128 * 64 * 2);

    const int mlp_grid = (n_nodes + 127) / 128;
    const int egrid = (n_edges + 255) / 256;
    const int nbuck = (n_nodes + CB - 1) / CB;
    const bool bucket_path = (nbuck <= NBMX && n_nodes < (1 << 20));

    // ---- prep (bucket hist + weights + x->bf16, one launch) ----
    hipMemsetAsync(bcnt, 0, (NBMX + 1) * sizeof(int), stream);
    prep_k<<<256 + (n_nodes * 8 + 255) / 256, 256, 0, stream>>>(
        x, xb, n_nodes * 8, W1a, W1b, W2a, W2b, WT1a, WT1b, WT2a, WT2b,
        dst, bcnt, bucket_path ? n_edges : 0, nbuck);

    // ---- CSR build ----
    if (bucket_path) {
        bscan_k<<<1, 256, 0, stream>>>(bcnt, boffs, gcur, nbuck);
        const bool vec4 = ((n_edges & 3) == 0);
        if (vec4)
            bucket_p1_k<true><<<256, 256, 0, stream>>>(src, dst, gcur, tmp, n_edges, nbuck);
        else
            bucket_p1_k<false><<<256, 256, 0, stream>>>(src, dst, gcur, tmp, n_edges, nbuck);
        bucket_csr_k<<<nbuck, 256, 0, stream>>>(tmp, boffs, offs, cnt, eidx, n_nodes);
    } else {
        hipMemsetAsync(cnt, 0, (size_t)n_nodes * sizeof(int), stream);
        hist_k<<<egrid, 256, 0, stream>>>(dst, cnt, n_edges);
        const int nb = (n_nodes + 2047) / 2048;
        scan_block_k<<<nb, 256, 0, stream>>>(cnt, offs, bsum, n_nodes);
        scan_bsum_k<<<1, 256, 0, stream>>>(bsum, nb);
        scan_add_k<<<nb, 256, 0, stream>>>(offs, cur, bsum, n_nodes);
        fill_k<<<egrid, 256, 0, stream>>>(src, dst, cur, eidx, n_edges);
    }

    // ---- layer 1 ----
    gather_agg_k<64><<<(n_nodes + 31) / 32, 256, 0, stream>>>(
        xb, offs, cnt, eidx, A, n_nodes);
    mlp_mfma_k<64, 128, true, true><<<mlp_grid, 256, 0, stream>>>(
        A, WT1a, b1a, WT1b, b1b, h, n_nodes);

    // ---- layer 2 ----
    gather_agg_k<128><<<(n_nodes + 15) / 16, 256, 0, stream>>>(
        h, offs, cnt, eidx, A, n_nodes);
    mlp_mfma_k<128, 64, false, false><<<mlp_grid, 256, 0, stream>>>(
        A, WT2a, b2a, WT2b, b2b, d_out, n_nodes);
}

// Round 11
// 201.517 us; speedup vs baseline: 1.0816x; 1.0816x over previous
//
#include <hip/hip_runtime.h>
#include <hip/hip_bf16.h>

// GIN 2-layer, bf16 feature pipeline + MFMA MLPs.
// r11 = r9 structure (measured 209us) + p1 processing 8 edges/thread/iter
// (halves barrier rounds). r10's prep-fusion and coalesced-flush reverted
// (net regression, -9us).

#define CB   512        // nodes per coarse bucket
#define NBMX 256        // max buckets (bucket path requires nbuck <= 256)
#define CAP  48         // LDS staged entries per bucket (p1)
#define FL   16         // flush granularity (16 x u32 = 64 B line)

typedef short  bf16x8 __attribute__((ext_vector_type(8)));
typedef float  f32x4  __attribute__((ext_vector_type(4)));

__device__ inline float bf2f(unsigned short u) {
    unsigned int t = ((unsigned int)u) << 16;
    return __builtin_bit_cast(float, t);
}
__device__ inline unsigned short f2bf(float f) {   // round-to-nearest-even
    unsigned int u = __builtin_bit_cast(unsigned int, f);
    u += 0x7fffu + ((u >> 16) & 1u);
    return (unsigned short)(u >> 16);
}

// ---------------- prep: weights transpose->bf16 + x->bf16, one launch --------
__global__ __launch_bounds__(256) void prep_k(
    const float* __restrict__ x, unsigned short* __restrict__ xb, int n8,
    const float* __restrict__ W1a, const float* __restrict__ W1b,
    const float* __restrict__ W2a, const float* __restrict__ W2b,
    unsigned short* __restrict__ T1a, unsigned short* __restrict__ T1b,
    unsigned short* __restrict__ T2a, unsigned short* __restrict__ T2b)
{
    int b = blockIdx.x;
    if (b < 192) {                       // WT[n][k] = bf16(W[k][n])
        int idx = b * 256 + threadIdx.x;
        const float* W; unsigned short* T; int K, N;
        if (idx < 8192)        { W = W1a; T = T1a; K = 64;  N = 128; }
        else if (idx < 24576)  { idx -= 8192;  W = W1b; T = T1b; K = 128; N = 128; }
        else if (idx < 40960)  { idx -= 24576; W = W2a; T = T2a; K = 128; N = 128; }
        else if (idx < 49152)  { idx -= 40960; W = W2b; T = T2b; K = 128; N = 64; }
        else return;
        int n = idx / K, k = idx - n * K;
        T[idx] = f2bf(W[(size_t)k * N + n]);
    } else {                             // x -> bf16
        int i = (b - 192) * 256 + threadIdx.x;
        if (i >= n8) return;
        const float4* p = reinterpret_cast<const float4*>(x + (size_t)i * 8);
        float4 a = p[0], c = p[1];
        union { unsigned short us[8]; uint4 v; } o;
        o.us[0] = f2bf(a.x); o.us[1] = f2bf(a.y); o.us[2] = f2bf(a.z); o.us[3] = f2bf(a.w);
        o.us[4] = f2bf(c.x); o.us[5] = f2bf(c.y); o.us[6] = f2bf(c.z); o.us[7] = f2bf(c.w);
        *reinterpret_cast<uint4*>(xb + (size_t)i * 8) = o.v;
    }
}

// ---------------- per-bucket histogram (LDS, few global atomics) -------------
__global__ __launch_bounds__(256) void bhist_k(
    const int* __restrict__ dst, int* __restrict__ bcnt, int n_edges, int nbuck)
{
    __shared__ int lh[NBMX];
    const int tid = threadIdx.x;
    for (int b = tid; b < nbuck; b += 256) lh[b] = 0;
    __syncthreads();
    const int e4 = n_edges >> 2;
    const int stride = gridDim.x * 256;
    for (int i4 = blockIdx.x * 256 + tid; i4 < e4; i4 += stride) {
        int4 dv = reinterpret_cast<const int4*>(dst)[i4];
        atomicAdd(&lh[dv.x / CB], 1);
        atomicAdd(&lh[dv.y / CB], 1);
        atomicAdd(&lh[dv.z / CB], 1);
        atomicAdd(&lh[dv.w / CB], 1);
    }
    if (blockIdx.x == 0 && tid < (n_edges & 3))
        atomicAdd(&lh[dst[e4 * 4 + tid] / CB], 1);
    __syncthreads();
    for (int b = tid; b < nbuck; b += 256) {
        int v = lh[b];
        if (v) atomicAdd(&bcnt[b], v);
    }
}

// ---------------- bucket scan (1 block): boffs + gcur ----------------
__global__ __launch_bounds__(256) void bscan_k(
    const int* __restrict__ bcnt, int* __restrict__ boffs,
    int* __restrict__ gcur, int nbuck)
{
    __shared__ int s[256];
    const int tid = threadIdx.x;
    int v = (tid < nbuck) ? bcnt[tid] : 0;
    s[tid] = v; __syncthreads();
    #pragma unroll
    for (int d = 1; d < 256; d <<= 1) {
        int t = (tid >= d) ? s[tid - d] : 0;
        __syncthreads();
        s[tid] += t;
        __syncthreads();
    }
    if (tid < nbuck) {
        int excl = s[tid] - v;
        boffs[tid] = excl;
        gcur[tid] = excl;
        if (tid == nbuck - 1) boffs[nbuck] = s[tid];
    }
}

// ---------------- pass 1: LDS-staged binning, 8 edges/thread/iter ------------
template<bool VEC4>
__global__ __launch_bounds__(256) void bucket_p1_k(
    const int* __restrict__ src, const int* __restrict__ dst,
    int* __restrict__ gcur, unsigned int* __restrict__ tmp,
    int n_edges, int nb)
{
    __shared__ unsigned int stage[NBMX][CAP];
    __shared__ int scnt[NBMX];
    const int tid = threadIdx.x;
    for (int b = tid; b < nb; b += 256) scnt[b] = 0;
    __syncthreads();

    const int e8total = n_edges >> 3;        // 8-edge chunks
    const int stride = gridDim.x * 256;
    const int iters = (e8total + stride - 1) / stride;

    for (int it = 0; it < iters; ++it) {
        int i8 = it * stride + blockIdx.x * 256 + tid;
        if (i8 < e8total) {
            int s8[8], d8[8];
            if constexpr (VEC4) {
                int4 sv0 = reinterpret_cast<const int4*>(src)[i8 * 2];
                int4 sv1 = reinterpret_cast<const int4*>(src)[i8 * 2 + 1];
                int4 dv0 = reinterpret_cast<const int4*>(dst)[i8 * 2];
                int4 dv1 = reinterpret_cast<const int4*>(dst)[i8 * 2 + 1];
                s8[0]=sv0.x; s8[1]=sv0.y; s8[2]=sv0.z; s8[3]=sv0.w;
                s8[4]=sv1.x; s8[5]=sv1.y; s8[6]=sv1.z; s8[7]=sv1.w;
                d8[0]=dv0.x; d8[1]=dv0.y; d8[2]=dv0.z; d8[3]=dv0.w;
                d8[4]=dv1.x; d8[5]=dv1.y; d8[6]=dv1.z; d8[7]=dv1.w;
            } else {
                #pragma unroll
                for (int j = 0; j < 8; ++j) { s8[j]=src[i8*8+j]; d8[j]=dst[i8*8+j]; }
            }
            #pragma unroll
            for (int j = 0; j < 8; ++j) {
                int dd = d8[j];
                int b = dd / CB;
                unsigned int entry = (unsigned int)s8[j] | ((unsigned int)(dd - b * CB) << 20);
                int slot = atomicAdd(&scnt[b], 1);
                if (slot < CAP) stage[b][slot] = entry;
                else { int p = atomicAdd(&gcur[b], 1); tmp[p] = entry; }   // overflow (rare)
            }
        }
        __syncthreads();
        // flush phase: thread b owns bucket b (r9-proven form)
        if (tid < nb) {
            int m = scnt[tid]; if (m > CAP) m = CAP;
            while (m >= FL) {
                int base = atomicAdd(&gcur[tid], FL);
                #pragma unroll
                for (int q = 0; q < FL; ++q)
                    tmp[base + q] = stage[tid][m - FL + q];
                m -= FL;
            }
            scnt[tid] = m;
        }
        __syncthreads();
    }
    // drain leftovers
    if (tid < nb) {
        int m = scnt[tid]; if (m > CAP) m = CAP;
        if (m > 0) {
            int base = atomicAdd(&gcur[tid], m);
            for (int q = 0; q < m; ++q) tmp[base + q] = stage[tid][q];
        }
    }
    // scalar tail (n_edges % 8)
    if (blockIdx.x == 0 && tid < (n_edges & 7)) {
        int e = e8total * 8 + tid;
        int dd = dst[e];
        int b = dd / CB;
        unsigned int entry = (unsigned int)src[e] | ((unsigned int)(dd - b * CB) << 20);
        int p = atomicAdd(&gcur[b], 1);
        tmp[p] = entry;
    }
}

// ---------------- pass 2: bucket-local count + scan + scatter (proven) -------
__global__ __launch_bounds__(256) void bucket_csr_k(
    const unsigned int* __restrict__ tmp, const int* __restrict__ boffs,
    int* __restrict__ offs, int* __restrict__ cnt, int* __restrict__ eidx,
    int n_nodes)
{
    __shared__ int lcnt[CB];
    __shared__ int lcur[CB];
    __shared__ int ssum[256];
    const int b = blockIdx.x;
    const int tid = threadIdx.x;
    const int node0 = b * CB;
    const int nn = min(CB, n_nodes - node0);
    const int lo = boffs[b], hi = boffs[b + 1];

    for (int i = tid; i < CB; i += 256) lcnt[i] = 0;
    __syncthreads();
    for (int i = lo + tid; i < hi; i += 256)
        atomicAdd(&lcnt[tmp[i] >> 20], 1);
    __syncthreads();

    int a0 = lcnt[tid * 2], a1 = lcnt[tid * 2 + 1];
    int tsum = a0 + a1;
    ssum[tid] = tsum; __syncthreads();
    #pragma unroll
    for (int d = 1; d < 256; d <<= 1) {
        int t = (tid >= d) ? ssum[tid - d] : 0;
        __syncthreads();
        ssum[tid] += t;
        __syncthreads();
    }
    int run = ssum[tid] - tsum;

    lcur[tid * 2]     = run;
    lcur[tid * 2 + 1] = run + a0;
    int g0 = node0 + tid * 2;
    if (tid * 2 < nn)     { offs[g0]     = lo + run;      cnt[g0]     = a0; }
    if (tid * 2 + 1 < nn) { offs[g0 + 1] = lo + run + a0; cnt[g0 + 1] = a1; }
    __syncthreads();

    for (int i = lo + tid; i < hi; i += 256) {
        unsigned int v = tmp[i];
        int p = atomicAdd(&lcur[v >> 20], 1);
        eidx[lo + p] = (int)(v & 0xFFFFFu);
    }
}

// ---------------- fallback pipeline (nbuck > NBMX) ----------------
__global__ __launch_bounds__(256) void hist_k(
    const int* __restrict__ dst, int* __restrict__ cnt, int n_edges)
{
    int e = blockIdx.x * 256 + threadIdx.x;
    if (e < n_edges) atomicAdd(&cnt[dst[e]], 1);
}

__global__ __launch_bounds__(256) void scan_block_k(
    const int* __restrict__ cnt, int* __restrict__ offs, int* __restrict__ bsum, int n)
{
    __shared__ int s[256];
    const int tid = threadIdx.x;
    const int base = blockIdx.x * 2048 + tid * 8;
    int v[8]; int tsum = 0;
    #pragma unroll
    for (int j = 0; j < 8; ++j) {
        int idx = base + j;
        v[j] = (idx < n) ? cnt[idx] : 0;
        tsum += v[j];
    }
    s[tid] = tsum; __syncthreads();
    #pragma unroll
    for (int d = 1; d < 256; d <<= 1) {
        int t = (tid >= d) ? s[tid - d] : 0;
        __syncthreads();
        s[tid] += t;
        __syncthreads();
    }
    int run = s[tid] - tsum;
    #pragma unroll
    for (int j = 0; j < 8; ++j) {
        int idx = base + j;
        if (idx < n) offs[idx] = run;
        run += v[j];
    }
    if (tid == 255) bsum[blockIdx.x] = s[255];
}

__global__ __launch_bounds__(256) void scan_bsum_k(int* __restrict__ bsum, int nb)
{
    __shared__ int s[256];
    const int tid = threadIdx.x;
    int v = (tid < nb) ? bsum[tid] : 0;
    s[tid] = v; __syncthreads();
    #pragma unroll
    for (int d = 1; d < 256; d <<= 1) {
        int t = (tid >= d) ? s[tid - d] : 0;
        __syncthreads();
        s[tid] += t;
        __syncthreads();
    }
    if (tid < nb) bsum[tid] = s[tid] - v;
}

__global__ __launch_bounds__(256) void scan_add_k(
    int* __restrict__ offs, int* __restrict__ cur, const int* __restrict__ bsum, int n)
{
    const int b = bsum[blockIdx.x];
    const int base = blockIdx.x * 2048 + threadIdx.x * 8;
    #pragma unroll
    for (int j = 0; j < 8; ++j) {
        int idx = base + j;
        if (idx < n) { int o = offs[idx] + b; offs[idx] = o; cur[idx] = o; }
    }
}

__global__ __launch_bounds__(256) void fill_k(
    const int* __restrict__ src, const int* __restrict__ dst,
    int* __restrict__ cur, int* __restrict__ eidx, int n_edges)
{
    int e = blockIdx.x * 256 + threadIdx.x;
    if (e < n_edges) {
        int p = atomicAdd(&cur[dst[e]], 1);
        eidx[p] = src[e];
    }
}

// ---------------- gather aggregation: A = self + sum(nbrs), 4-edge unroll ----
template<int C>
__global__ __launch_bounds__(256) void gather_agg_k(
    const unsigned short* __restrict__ h, const int* __restrict__ offs,
    const int* __restrict__ cnt, const int* __restrict__ eidx,
    unsigned short* __restrict__ A, int n_nodes)
{
    constexpr int TPN = C / 8;
    constexpr int NPB = 256 / TPN;
    const int node = blockIdx.x * NPB + threadIdx.x / TPN;
    const int lane = threadIdx.x % TPN;
    if (node >= n_nodes) return;
    const size_t coff = (size_t)lane * 8;

    float acc[8];
    {
        uint4 v = *reinterpret_cast<const uint4*>(h + (size_t)node * C + coff);
        const unsigned short* u = (const unsigned short*)&v;
        #pragma unroll
        for (int j = 0; j < 8; ++j) acc[j] = bf2f(u[j]);
    }
    const int beg = offs[node], end = beg + cnt[node];
    int p = beg;
    for (; p + 4 <= end; p += 4) {
        int s0 = eidx[p], s1 = eidx[p + 1], s2 = eidx[p + 2], s3 = eidx[p + 3];
        uint4 v0 = *reinterpret_cast<const uint4*>(h + (size_t)s0 * C + coff);
        uint4 v1 = *reinterpret_cast<const uint4*>(h + (size_t)s1 * C + coff);
        uint4 v2 = *reinterpret_cast<const uint4*>(h + (size_t)s2 * C + coff);
        uint4 v3 = *reinterpret_cast<const uint4*>(h + (size_t)s3 * C + coff);
        const unsigned short* u0 = (const unsigned short*)&v0;
        const unsigned short* u1 = (const unsigned short*)&v1;
        const unsigned short* u2 = (const unsigned short*)&v2;
        const unsigned short* u3 = (const unsigned short*)&v3;
        #pragma unroll
        for (int j = 0; j < 8; ++j)
            acc[j] += (bf2f(u0[j]) + bf2f(u1[j])) + (bf2f(u2[j]) + bf2f(u3[j]));
    }
    if (p + 2 <= end) {
        int s0 = eidx[p], s1 = eidx[p + 1];
        uint4 v0 = *reinterpret_cast<const uint4*>(h + (size_t)s0 * C + coff);
        uint4 v1 = *reinterpret_cast<const uint4*>(h + (size_t)s1 * C + coff);
        const unsigned short* u0 = (const unsigned short*)&v0;
        const unsigned short* u1 = (const unsigned short*)&v1;
        #pragma unroll
        for (int j = 0; j < 8; ++j) acc[j] += bf2f(u0[j]) + bf2f(u1[j]);
        p += 2;
    }
    if (p < end) {
        uint4 v0 = *reinterpret_cast<const uint4*>(h + (size_t)eidx[p] * C + coff);
        const unsigned short* u0 = (const unsigned short*)&v0;
        #pragma unroll
        for (int j = 0; j < 8; ++j) acc[j] += bf2f(u0[j]);
    }
    union { unsigned short us[8]; uint4 v; } o;
    #pragma unroll
    for (int j = 0; j < 8; ++j) o.us[j] = f2bf(acc[j]);
    *reinterpret_cast<uint4*>(A + (size_t)node * C + coff) = o.v;
}

// ---------------- fused 2-GEMM MLP via MFMA bf16, 128-row tile (proven r9) ---
template<int K1, int N2, bool RELU_OUT, bool OUT_BF16>
__global__ __launch_bounds__(256) void mlp_mfma_k(
    const unsigned short* __restrict__ Ain,
    const unsigned short* __restrict__ WTa,
    const float* __restrict__ ba,
    const unsigned short* __restrict__ WTb,
    const float* __restrict__ bb,
    void* __restrict__ outp, int n_nodes)
{
    constexpr int KS1 = K1 / 32;
    constexpr int NT2 = N2 / 16;
    static_assert(128 * K1 <= 128 * 128, "sA fits sAM");
    static_assert(128 * N2 * (OUT_BF16 ? 2 : 4) <= 128 * 128 * 2, "out stage fits sAM");

    __shared__ __align__(16) unsigned short sAM[128 * 128];  // sA / sMid / out
    __shared__ __align__(16) unsigned short sWa[128 * K1];
    __shared__ __align__(16) unsigned short sWb[N2 * 128];

    const int tid = threadIdx.x;
    const int wave = tid >> 6, lane = tid & 63;
    const int rc = lane & 15;
    const int kg = lane >> 4;
    const int rowBlock = blockIdx.x * 128;

    {   // stage A [128][K1] (guarded rows), swizzled
        constexpr int CPR = K1 / 8;
        #pragma unroll
        for (int f = tid; f < 128 * CPR; f += 256) {
            int r = f / CPR, c = f - r * CPR;
            uint4 v = make_uint4(0u, 0u, 0u, 0u);
            int gr = rowBlock + r;
            if (gr < n_nodes)
                v = *reinterpret_cast<const uint4*>(Ain + (size_t)gr * K1 + c * 8);
            int byte = r * (K1 * 2) + ((c * 16) ^ ((r & 7) << 4));
            *reinterpret_cast<uint4*>((char*)sAM + byte) = v;
        }
    }
    {   // stage WTa [128][K1], swizzled
        constexpr int CPR = K1 / 8;
        #pragma unroll
        for (int f = tid; f < 128 * CPR; f += 256) {
            int r = f / CPR, c = f - r * CPR;
            uint4 v = *reinterpret_cast<const uint4*>(WTa + (size_t)r * K1 + c * 8);
            int byte = r * (K1 * 2) + ((c * 16) ^ ((r & 7) << 4));
            *reinterpret_cast<uint4*>((char*)sWa + byte) = v;
        }
    }
    {   // stage WTb [N2][128], swizzled
        #pragma unroll
        for (int f = tid; f < N2 * 16; f += 256) {
            int r = f / 16, c = f - r * 16;
            uint4 v = *reinterpret_cast<const uint4*>(WTb + (size_t)r * 128 + c * 8);
            int byte = r * 256 + ((c * 16) ^ ((r & 7) << 4));
            *reinterpret_cast<uint4*>((char*)sWb + byte) = v;
        }
    }
    __syncthreads();

    // ---- GEMM1: (128 x K1) @ (K1 x 128) ----
    bf16x8 af[2][KS1];
    #pragma unroll
    for (int rt = 0; rt < 2; ++rt)
        #pragma unroll
        for (int ks = 0; ks < KS1; ++ks) {
            int r = wave * 32 + rt * 16 + rc;
            int byte = r * (K1 * 2) + (((ks * 32 + kg * 8) * 2) ^ ((r & 7) << 4));
            af[rt][ks] = *reinterpret_cast<const bf16x8*>((const char*)sAM + byte);
        }
    __syncthreads();   // all sA reads complete before sMid overwrite

    f32x4 acc1[2][8];
    #pragma unroll
    for (int rt = 0; rt < 2; ++rt)
        #pragma unroll
        for (int n = 0; n < 8; ++n) acc1[rt][n] = (f32x4){0.f, 0.f, 0.f, 0.f};
    #pragma unroll
    for (int n = 0; n < 8; ++n) {
        int c = n * 16 + rc;
        #pragma unroll
        for (int ks = 0; ks < KS1; ++ks) {
            int byte = c * (K1 * 2) + (((ks * 32 + kg * 8) * 2) ^ ((c & 7) << 4));
            bf16x8 bfr = *reinterpret_cast<const bf16x8*>((const char*)sWa + byte);
            #pragma unroll
            for (int rt = 0; rt < 2; ++rt)
                acc1[rt][n] = __builtin_amdgcn_mfma_f32_16x16x32_bf16(
                    af[rt][ks], bfr, acc1[rt][n], 0, 0, 0);
        }
    }
    // epilogue 1: bias + relu -> sMid (= sAM) bf16 [128][128] swizzled
    #pragma unroll
    for (int n = 0; n < 8; ++n) {
        int c = n * 16 + rc;
        float bias = ba[c];
        #pragma unroll
        for (int rt = 0; rt < 2; ++rt)
            #pragma unroll
            for (int i = 0; i < 4; ++i) {
                int r = wave * 32 + rt * 16 + kg * 4 + i;
                float v = fmaxf(acc1[rt][n][i] + bias, 0.f);
                int byte = r * 256 + ((c * 2) ^ ((r & 7) << 4));
                *reinterpret_cast<unsigned short*>((char*)sAM + byte) = f2bf(v);
            }
    }
    __syncthreads();

    // ---- GEMM2: (128 x 128) @ (128 x N2) ----
    bf16x8 mf[2][4];
    #pragma unroll
    for (int rt = 0; rt < 2; ++rt)
        #pragma unroll
        for (int ks = 0; ks < 4; ++ks) {
            int r = wave * 32 + rt * 16 + rc;
            int byte = r * 256 + (((ks * 32 + kg * 8) * 2) ^ ((r & 7) << 4));
            mf[rt][ks] = *reinterpret_cast<const bf16x8*>((const char*)sAM + byte);
        }
    f32x4 acc2[2][NT2];
    #pragma unroll
    for (int rt = 0; rt < 2; ++rt)
        #pragma unroll
        for (int n = 0; n < NT2; ++n) acc2[rt][n] = (f32x4){0.f, 0.f, 0.f, 0.f};
    #pragma unroll
    for (int n = 0; n < NT2; ++n) {
        int c = n * 16 + rc;
        #pragma unroll
        for (int ks = 0; ks < 4; ++ks) {
            int byte = c * 256 + (((ks * 32 + kg * 8) * 2) ^ ((c & 7) << 4));
            bf16x8 bfr = *reinterpret_cast<const bf16x8*>((const char*)sWb + byte);
            #pragma unroll
            for (int rt = 0; rt < 2; ++rt)
                acc2[rt][n] = __builtin_amdgcn_mfma_f32_16x16x32_bf16(
                    mf[rt][ks], bfr, acc2[rt][n], 0, 0, 0);
        }
    }
    __syncthreads();   // all sMid reads done before out-staging overwrite

    // ---- epilogue 2: bias [+relu] -> stage in sAM -> coalesced store ----
    if constexpr (OUT_BF16) {
        #pragma unroll
        for (int n = 0; n < NT2; ++n) {
            int c = n * 16 + rc;
            float bias = bb[c];
            #pragma unroll
            for (int rt = 0; rt < 2; ++rt)
                #pragma unroll
                for (int i = 0; i < 4; ++i) {
                    int r = wave * 32 + rt * 16 + kg * 4 + i;
                    float v = acc2[rt][n][i] + bias;
                    if (RELU_OUT) v = fmaxf(v, 0.f);
                    sAM[r * N2 + c] = f2bf(v);
                }
        }
        __syncthreads();
        unsigned short* out = (unsigned short*)outp;
        constexpr int CPR = N2 / 8;
        #pragma unroll
        for (int f = tid; f < 128 * CPR; f += 256) {
            int r = f / CPR, c = f - r * CPR;
            int gr = rowBlock + r;
            if (gr < n_nodes)
                *reinterpret_cast<uint4*>(out + (size_t)gr * N2 + c * 8) =
                    *reinterpret_cast<const uint4*>(sAM + r * N2 + c * 8);
        }
    } else {
        float* sOut = reinterpret_cast<float*>(sAM);   // [128][N2] f32
        #pragma unroll
        for (int n = 0; n < NT2; ++n) {
            int c = n * 16 + rc;
            float bias = bb[c];
            #pragma unroll
            for (int rt = 0; rt < 2; ++rt)
                #pragma unroll
                for (int i = 0; i < 4; ++i) {
                    int r = wave * 32 + rt * 16 + kg * 4 + i;
                    float v = acc2[rt][n][i] + bias;
                    if (RELU_OUT) v = fmaxf(v, 0.f);
                    sOut[r * N2 + c] = v;
                }
        }
        __syncthreads();
        float* out = (float*)outp;
        constexpr int CPR = N2 / 4;
        #pragma unroll
        for (int f = tid; f < 128 * CPR; f += 256) {
            int r = f / CPR, c = f - r * CPR;
            int gr = rowBlock + r;
            if (gr < n_nodes)
                *reinterpret_cast<float4*>(out + (size_t)gr * N2 + c * 4) =
                    *reinterpret_cast<const float4*>(sOut + r * N2 + c * 4);
        }
    }
}

extern "C" void kernel_launch(void* const* d_in, const int* in_sizes, int n_in,
                              void* d_out, int out_size, void* d_ws, size_t ws_size,
                              hipStream_t stream)
{
    const float* x   = (const float*)d_in[0];
    const int*   ei  = (const int*)d_in[1];
    const float* W1a = (const float*)d_in[2];
    const float* b1a = (const float*)d_in[3];
    const float* W1b = (const float*)d_in[4];
    const float* b1b = (const float*)d_in[5];
    const float* W2a = (const float*)d_in[6];
    const float* b2a = (const float*)d_in[7];
    const float* W2b = (const float*)d_in[8];
    const float* b2b = (const float*)d_in[9];

    const int n_nodes = in_sizes[0] / 64;
    const int n_edges = in_sizes[1] / 2;
    const int* src = ei;
    const int* dst = ei + n_edges;

    char* ws = (char*)d_ws;
    size_t o = 0;
    auto alloc = [&](size_t bytes) -> char* {
        char* p = ws + o;
        o += (bytes + 255) & ~(size_t)255;
        return p;
    };
    unsigned short* A    = (unsigned short*)alloc((size_t)n_nodes * 128 * 2);
    unsigned short* h    = (unsigned short*)alloc((size_t)n_nodes * 128 * 2);
    unsigned short* xb   = (unsigned short*)alloc((size_t)n_nodes * 64 * 2);
    int* eidx = (int*)alloc((size_t)n_edges * 4);
    unsigned int* tmp = (unsigned int*)alloc((size_t)n_edges * 4);
    int* cnt  = (int*)alloc((size_t)n_nodes * 4);
    int* offs = (int*)alloc((size_t)n_nodes * 4);
    int* cur  = (int*)alloc((size_t)n_nodes * 4);
    int* bsum = (int*)alloc(256 * 4);
    int* gcur = (int*)alloc(NBMX * 4);
    int* bcnt = (int*)alloc((NBMX + 1) * 4);
    int* boffs = (int*)alloc((NBMX + 1) * 4);
    unsigned short* WT1a = (unsigned short*)alloc(64 * 128 * 2);
    unsigned short* WT1b = (unsigned short*)alloc(128 * 128 * 2);
    unsigned short* WT2a = (unsigned short*)alloc(128 * 128 * 2);
    unsigned short* WT2b = (unsigned short*)alloc(128 * 64 * 2);

    const int mlp_grid = (n_nodes + 127) / 128;
    const int egrid = (n_edges + 255) / 256;
    const int nbuck = (n_nodes + CB - 1) / CB;

    // ---- prep (weights + x->bf16) ----
    prep_k<<<192 + (n_nodes * 8 + 255) / 256, 256, 0, stream>>>(
        x, xb, n_nodes * 8, W1a, W1b, W2a, W2b, WT1a, WT1b, WT2a, WT2b);

    // ---- CSR build ----
    if (nbuck <= NBMX && n_nodes < (1 << 20)) {
        hipMemsetAsync(bcnt, 0, (NBMX + 1) * sizeof(int), stream);
        bhist_k<<<128, 256, 0, stream>>>(dst, bcnt, n_edges, nbuck);
        bscan_k<<<1, 256, 0, stream>>>(bcnt, boffs, gcur, nbuck);
        const bool vec4 = ((n_edges & 7) == 0);
        if (vec4)
            bucket_p1_k<true><<<256, 256, 0, stream>>>(src, dst, gcur, tmp, n_edges, nbuck);
        else
            bucket_p1_k<false><<<256, 256, 0, stream>>>(src, dst, gcur, tmp, n_edges, nbuck);
        bucket_csr_k<<<nbuck, 256, 0, stream>>>(tmp, boffs, offs, cnt, eidx, n_nodes);
    } else {
        hipMemsetAsync(cnt, 0, (size_t)n_nodes * sizeof(int), stream);
        hist_k<<<egrid, 256, 0, stream>>>(dst, cnt, n_edges);
        const int nb = (n_nodes + 2047) / 2048;
        scan_block_k<<<nb, 256, 0, stream>>>(cnt, offs, bsum, n_nodes);
        scan_bsum_k<<<1, 256, 0, stream>>>(bsum, nb);
        scan_add_k<<<nb, 256, 0, stream>>>(offs, cur, bsum, n_nodes);
        fill_k<<<egrid, 256, 0, stream>>>(src, dst, cur, eidx, n_edges);
    }

    // ---- layer 1 ----
    gather_agg_k<64><<<(n_nodes + 31) / 32, 256, 0, stream>>>(
        xb, offs, cnt, eidx, A, n_nodes);
    mlp_mfma_k<64, 128, true, true><<<mlp_grid, 256, 0, stream>>>(
        A, WT1a, b1a, WT1b, b1b, h, n_nodes);

    // ---- layer 2 ----
    gather_agg_k<128><<<(n_nodes + 15) / 16, 256, 0, stream>>>(
        h, offs, cnt, eidx, A, n_nodes);
    mlp_mfma_k<128, 64, false, false><<<mlp_grid, 256, 0, stream>>>(
        A, WT2a, b2a, WT2b, b2b, d_out, n_nodes);
}

// Round 13
// 176.924 us; speedup vs baseline: 1.2320x; 1.1390x over previous
//
#include <hip/hip_runtime.h>
#include <hip/hip_bf16.h>

// GIN 2-layer, bf16 feature pipeline + MFMA MLPs.
// r13 = r12 (fp8 e4m3 storage for inter-layer h, halving gather-2 traffic)
// with the cvt_pk_fp8_f32 word-select made a compile-time constant.

#define CB   512        // nodes per coarse bucket
#define NBMX 256        // max buckets (bucket path requires nbuck <= 256)
#define CAP  48         // LDS staged entries per bucket (p1)
#define FL   16         // flush granularity (16 x u32 = 64 B line)

typedef short  bf16x8 __attribute__((ext_vector_type(8)));
typedef float  f32x4  __attribute__((ext_vector_type(4)));
typedef float  f32x2  __attribute__((ext_vector_type(2)));

__device__ inline float bf2f(unsigned short u) {
    unsigned int t = ((unsigned int)u) << 16;
    return __builtin_bit_cast(float, t);
}
__device__ inline unsigned short f2bf(float f) {   // round-to-nearest-even
    unsigned int u = __builtin_bit_cast(unsigned int, f);
    u += 0x7fffu + ((u >> 16) & 1u);
    return (unsigned short)(u >> 16);
}
// fp8 e4m3 (OCP on gfx950) pack/unpack via HW converts.
// Word-select of cvt_pk_fp8_f32 must be a literal -> template.
template<bool HI>
__device__ inline unsigned int pk_fp8(float a, float b, unsigned int old) {
    return (unsigned int)__builtin_amdgcn_cvt_pk_fp8_f32(a, b, (int)old, HI);
}
__device__ inline void unpk4(unsigned int w, float* o) {
    f32x2 lo = __builtin_amdgcn_cvt_pk_f32_fp8(w, false);
    f32x2 hi = __builtin_amdgcn_cvt_pk_f32_fp8(w, true);
    o[0] = lo.x; o[1] = lo.y; o[2] = hi.x; o[3] = hi.y;
}

// ---------------- prep: weights transpose->bf16 + x->bf16, one launch --------
__global__ __launch_bounds__(256) void prep_k(
    const float* __restrict__ x, unsigned short* __restrict__ xb, int n8,
    const float* __restrict__ W1a, const float* __restrict__ W1b,
    const float* __restrict__ W2a, const float* __restrict__ W2b,
    unsigned short* __restrict__ T1a, unsigned short* __restrict__ T1b,
    unsigned short* __restrict__ T2a, unsigned short* __restrict__ T2b)
{
    int b = blockIdx.x;
    if (b < 192) {                       // WT[n][k] = bf16(W[k][n])
        int idx = b * 256 + threadIdx.x;
        const float* W; unsigned short* T; int K, N;
        if (idx < 8192)        { W = W1a; T = T1a; K = 64;  N = 128; }
        else if (idx < 24576)  { idx -= 8192;  W = W1b; T = T1b; K = 128; N = 128; }
        else if (idx < 40960)  { idx -= 24576; W = W2a; T = T2a; K = 128; N = 128; }
        else if (idx < 49152)  { idx -= 40960; W = W2b; T = T2b; K = 128; N = 64; }
        else return;
        int n = idx / K, k = idx - n * K;
        T[idx] = f2bf(W[(size_t)k * N + n]);
    } else {                             // x -> bf16
        int i = (b - 192) * 256 + threadIdx.x;
        if (i >= n8) return;
        const float4* p = reinterpret_cast<const float4*>(x + (size_t)i * 8);
        float4 a = p[0], c = p[1];
        union { unsigned short us[8]; uint4 v; } o;
        o.us[0] = f2bf(a.x); o.us[1] = f2bf(a.y); o.us[2] = f2bf(a.z); o.us[3] = f2bf(a.w);
        o.us[4] = f2bf(c.x); o.us[5] = f2bf(c.y); o.us[6] = f2bf(c.z); o.us[7] = f2bf(c.w);
        *reinterpret_cast<uint4*>(xb + (size_t)i * 8) = o.v;
    }
}

// ---------------- per-bucket histogram (LDS, few global atomics) -------------
__global__ __launch_bounds__(256) void bhist_k(
    const int* __restrict__ dst, int* __restrict__ bcnt, int n_edges, int nbuck)
{
    __shared__ int lh[NBMX];
    const int tid = threadIdx.x;
    for (int b = tid; b < nbuck; b += 256) lh[b] = 0;
    __syncthreads();
    const int e4 = n_edges >> 2;
    const int stride = gridDim.x * 256;
    for (int i4 = blockIdx.x * 256 + tid; i4 < e4; i4 += stride) {
        int4 dv = reinterpret_cast<const int4*>(dst)[i4];
        atomicAdd(&lh[dv.x / CB], 1);
        atomicAdd(&lh[dv.y / CB], 1);
        atomicAdd(&lh[dv.z / CB], 1);
        atomicAdd(&lh[dv.w / CB], 1);
    }
    if (blockIdx.x == 0 && tid < (n_edges & 3))
        atomicAdd(&lh[dst[e4 * 4 + tid] / CB], 1);
    __syncthreads();
    for (int b = tid; b < nbuck; b += 256) {
        int v = lh[b];
        if (v) atomicAdd(&bcnt[b], v);
    }
}

// ---------------- bucket scan (1 block): boffs + gcur ----------------
__global__ __launch_bounds__(256) void bscan_k(
    const int* __restrict__ bcnt, int* __restrict__ boffs,
    int* __restrict__ gcur, int nbuck)
{
    __shared__ int s[256];
    const int tid = threadIdx.x;
    int v = (tid < nbuck) ? bcnt[tid] : 0;
    s[tid] = v; __syncthreads();
    #pragma unroll
    for (int d = 1; d < 256; d <<= 1) {
        int t = (tid >= d) ? s[tid - d] : 0;
        __syncthreads();
        s[tid] += t;
        __syncthreads();
    }
    if (tid < nbuck) {
        int excl = s[tid] - v;
        boffs[tid] = excl;
        gcur[tid] = excl;
        if (tid == nbuck - 1) boffs[nbuck] = s[tid];
    }
}

// ---------------- pass 1: LDS-staged binning, 8 edges/thread/iter (r11) ------
template<bool VEC4>
__global__ __launch_bounds__(256) void bucket_p1_k(
    const int* __restrict__ src, const int* __restrict__ dst,
    int* __restrict__ gcur, unsigned int* __restrict__ tmp,
    int n_edges, int nb)
{
    __shared__ unsigned int stage[NBMX][CAP];
    __shared__ int scnt[NBMX];
    const int tid = threadIdx.x;
    for (int b = tid; b < nb; b += 256) scnt[b] = 0;
    __syncthreads();

    const int e8total = n_edges >> 3;
    const int stride = gridDim.x * 256;
    const int iters = (e8total + stride - 1) / stride;

    for (int it = 0; it < iters; ++it) {
        int i8 = it * stride + blockIdx.x * 256 + tid;
        if (i8 < e8total) {
            int s8[8], d8[8];
            if constexpr (VEC4) {
                int4 sv0 = reinterpret_cast<const int4*>(src)[i8 * 2];
                int4 sv1 = reinterpret_cast<const int4*>(src)[i8 * 2 + 1];
                int4 dv0 = reinterpret_cast<const int4*>(dst)[i8 * 2];
                int4 dv1 = reinterpret_cast<const int4*>(dst)[i8 * 2 + 1];
                s8[0]=sv0.x; s8[1]=sv0.y; s8[2]=sv0.z; s8[3]=sv0.w;
                s8[4]=sv1.x; s8[5]=sv1.y; s8[6]=sv1.z; s8[7]=sv1.w;
                d8[0]=dv0.x; d8[1]=dv0.y; d8[2]=dv0.z; d8[3]=dv0.w;
                d8[4]=dv1.x; d8[5]=dv1.y; d8[6]=dv1.z; d8[7]=dv1.w;
            } else {
                #pragma unroll
                for (int j = 0; j < 8; ++j) { s8[j]=src[i8*8+j]; d8[j]=dst[i8*8+j]; }
            }
            #pragma unroll
            for (int j = 0; j < 8; ++j) {
                int dd = d8[j];
                int b = dd / CB;
                unsigned int entry = (unsigned int)s8[j] | ((unsigned int)(dd - b * CB) << 20);
                int slot = atomicAdd(&scnt[b], 1);
                if (slot < CAP) stage[b][slot] = entry;
                else { int p = atomicAdd(&gcur[b], 1); tmp[p] = entry; }
            }
        }
        __syncthreads();
        if (tid < nb) {
            int m = scnt[tid]; if (m > CAP) m = CAP;
            while (m >= FL) {
                int base = atomicAdd(&gcur[tid], FL);
                #pragma unroll
                for (int q = 0; q < FL; ++q)
                    tmp[base + q] = stage[tid][m - FL + q];
                m -= FL;
            }
            scnt[tid] = m;
        }
        __syncthreads();
    }
    if (tid < nb) {
        int m = scnt[tid]; if (m > CAP) m = CAP;
        if (m > 0) {
            int base = atomicAdd(&gcur[tid], m);
            for (int q = 0; q < m; ++q) tmp[base + q] = stage[tid][q];
        }
    }
    if (blockIdx.x == 0 && tid < (n_edges & 7)) {
        int e = e8total * 8 + tid;
        int dd = dst[e];
        int b = dd / CB;
        unsigned int entry = (unsigned int)src[e] | ((unsigned int)(dd - b * CB) << 20);
        int p = atomicAdd(&gcur[b], 1);
        tmp[p] = entry;
    }
}

// ---------------- pass 2: bucket-local count + scan + scatter (proven) -------
__global__ __launch_bounds__(256) void bucket_csr_k(
    const unsigned int* __restrict__ tmp, const int* __restrict__ boffs,
    int* __restrict__ offs, int* __restrict__ cnt, int* __restrict__ eidx,
    int n_nodes)
{
    __shared__ int lcnt[CB];
    __shared__ int lcur[CB];
    __shared__ int ssum[256];
    const int b = blockIdx.x;
    const int tid = threadIdx.x;
    const int node0 = b * CB;
    const int nn = min(CB, n_nodes - node0);
    const int lo = boffs[b], hi = boffs[b + 1];

    for (int i = tid; i < CB; i += 256) lcnt[i] = 0;
    __syncthreads();
    for (int i = lo + tid; i < hi; i += 256)
        atomicAdd(&lcnt[tmp[i] >> 20], 1);
    __syncthreads();

    int a0 = lcnt[tid * 2], a1 = lcnt[tid * 2 + 1];
    int tsum = a0 + a1;
    ssum[tid] = tsum; __syncthreads();
    #pragma unroll
    for (int d = 1; d < 256; d <<= 1) {
        int t = (tid >= d) ? ssum[tid - d] : 0;
        __syncthreads();
        ssum[tid] += t;
        __syncthreads();
    }
    int run = ssum[tid] - tsum;

    lcur[tid * 2]     = run;
    lcur[tid * 2 + 1] = run + a0;
    int g0 = node0 + tid * 2;
    if (tid * 2 < nn)     { offs[g0]     = lo + run;      cnt[g0]     = a0; }
    if (tid * 2 + 1 < nn) { offs[g0 + 1] = lo + run + a0; cnt[g0 + 1] = a1; }
    __syncthreads();

    for (int i = lo + tid; i < hi; i += 256) {
        unsigned int v = tmp[i];
        int p = atomicAdd(&lcur[v >> 20], 1);
        eidx[lo + p] = (int)(v & 0xFFFFFu);
    }
}

// ---------------- fallback pipeline (nbuck > NBMX) ----------------
__global__ __launch_bounds__(256) void hist_k(
    const int* __restrict__ dst, int* __restrict__ cnt, int n_edges)
{
    int e = blockIdx.x * 256 + threadIdx.x;
    if (e < n_edges) atomicAdd(&cnt[dst[e]], 1);
}

__global__ __launch_bounds__(256) void scan_block_k(
    const int* __restrict__ cnt, int* __restrict__ offs, int* __restrict__ bsum, int n)
{
    __shared__ int s[256];
    const int tid = threadIdx.x;
    const int base = blockIdx.x * 2048 + tid * 8;
    int v[8]; int tsum = 0;
    #pragma unroll
    for (int j = 0; j < 8; ++j) {
        int idx = base + j;
        v[j] = (idx < n) ? cnt[idx] : 0;
        tsum += v[j];
    }
    s[tid] = tsum; __syncthreads();
    #pragma unroll
    for (int d = 1; d < 256; d <<= 1) {
        int t = (tid >= d) ? s[tid - d] : 0;
        __syncthreads();
        s[tid] += t;
        __syncthreads();
    }
    int run = s[tid] - tsum;
    #pragma unroll
    for (int j = 0; j < 8; ++j) {
        int idx = base + j;
        if (idx < n) offs[idx] = run;
        run += v[j];
    }
    if (tid == 255) bsum[blockIdx.x] = s[255];
}

__global__ __launch_bounds__(256) void scan_bsum_k(int* __restrict__ bsum, int nb)
{
    __shared__ int s[256];
    const int tid = threadIdx.x;
    int v = (tid < nb) ? bsum[tid] : 0;
    s[tid] = v; __syncthreads();
    #pragma unroll
    for (int d = 1; d < 256; d <<= 1) {
        int t = (tid >= d) ? s[tid - d] : 0;
        __syncthreads();
        s[tid] += t;
        __syncthreads();
    }
    if (tid < nb) bsum[tid] = s[tid] - v;
}

__global__ __launch_bounds__(256) void scan_add_k(
    int* __restrict__ offs, int* __restrict__ cur, const int* __restrict__ bsum, int n)
{
    const int b = bsum[blockIdx.x];
    const int base = blockIdx.x * 2048 + threadIdx.x * 8;
    #pragma unroll
    for (int j = 0; j < 8; ++j) {
        int idx = base + j;
        if (idx < n) { int o = offs[idx] + b; offs[idx] = o; cur[idx] = o; }
    }
}

__global__ __launch_bounds__(256) void fill_k(
    const int* __restrict__ src, const int* __restrict__ dst,
    int* __restrict__ cur, int* __restrict__ eidx, int n_edges)
{
    int e = blockIdx.x * 256 + threadIdx.x;
    if (e < n_edges) {
        int p = atomicAdd(&cur[dst[e]], 1);
        eidx[p] = src[e];
    }
}

// ---------------- gather (bf16, layer 1): A = self + sum(nbrs) ---------------
template<int C>
__global__ __launch_bounds__(256) void gather_agg_k(
    const unsigned short* __restrict__ h, const int* __restrict__ offs,
    const int* __restrict__ cnt, const int* __restrict__ eidx,
    unsigned short* __restrict__ A, int n_nodes)
{
    constexpr int TPN = C / 8;
    constexpr int NPB = 256 / TPN;
    const int node = blockIdx.x * NPB + threadIdx.x / TPN;
    const int lane = threadIdx.x % TPN;
    if (node >= n_nodes) return;
    const size_t coff = (size_t)lane * 8;

    float acc[8];
    {
        uint4 v = *reinterpret_cast<const uint4*>(h + (size_t)node * C + coff);
        const unsigned short* u = (const unsigned short*)&v;
        #pragma unroll
        for (int j = 0; j < 8; ++j) acc[j] = bf2f(u[j]);
    }
    const int beg = offs[node], end = beg + cnt[node];
    int p = beg;
    for (; p + 4 <= end; p += 4) {
        int s0 = eidx[p], s1 = eidx[p + 1], s2 = eidx[p + 2], s3 = eidx[p + 3];
        uint4 v0 = *reinterpret_cast<const uint4*>(h + (size_t)s0 * C + coff);
        uint4 v1 = *reinterpret_cast<const uint4*>(h + (size_t)s1 * C + coff);
        uint4 v2 = *reinterpret_cast<const uint4*>(h + (size_t)s2 * C + coff);
        uint4 v3 = *reinterpret_cast<const uint4*>(h + (size_t)s3 * C + coff);
        const unsigned short* u0 = (const unsigned short*)&v0;
        const unsigned short* u1 = (const unsigned short*)&v1;
        const unsigned short* u2 = (const unsigned short*)&v2;
        const unsigned short* u3 = (const unsigned short*)&v3;
        #pragma unroll
        for (int j = 0; j < 8; ++j)
            acc[j] += (bf2f(u0[j]) + bf2f(u1[j])) + (bf2f(u2[j]) + bf2f(u3[j]));
    }
    if (p + 2 <= end) {
        int s0 = eidx[p], s1 = eidx[p + 1];
        uint4 v0 = *reinterpret_cast<const uint4*>(h + (size_t)s0 * C + coff);
        uint4 v1 = *reinterpret_cast<const uint4*>(h + (size_t)s1 * C + coff);
        const unsigned short* u0 = (const unsigned short*)&v0;
        const unsigned short* u1 = (const unsigned short*)&v1;
        #pragma unroll
        for (int j = 0; j < 8; ++j) acc[j] += bf2f(u0[j]) + bf2f(u1[j]);
        p += 2;
    }
    if (p < end) {
        uint4 v0 = *reinterpret_cast<const uint4*>(h + (size_t)eidx[p] * C + coff);
        const unsigned short* u0 = (const unsigned short*)&v0;
        #pragma unroll
        for (int j = 0; j < 8; ++j) acc[j] += bf2f(u0[j]);
    }
    union { unsigned short us[8]; uint4 v; } o;
    #pragma unroll
    for (int j = 0; j < 8; ++j) o.us[j] = f2bf(acc[j]);
    *reinterpret_cast<uint4*>(A + (size_t)node * C + coff) = o.v;
}

// ---------------- gather (fp8, layer 2): A = self + sum(nbrs), bf16 out ------
// h8: [n][128] fp8 e4m3. TPN=8 threads/node, 16 ch/thread (one uint4 = 16 fp8).
__global__ __launch_bounds__(256) void gather_agg_fp8_k(
    const unsigned char* __restrict__ h8, const int* __restrict__ offs,
    const int* __restrict__ cnt, const int* __restrict__ eidx,
    unsigned short* __restrict__ A, int n_nodes)
{
    constexpr int C = 128;
    constexpr int TPN = 8;
    constexpr int NPB = 256 / TPN;   // 32 nodes/block
    const int node = blockIdx.x * NPB + threadIdx.x / TPN;
    const int lane = threadIdx.x % TPN;
    if (node >= n_nodes) return;
    const size_t boff = (size_t)lane * 16;

    float acc[16];
    {   // self
        uint4 v = *reinterpret_cast<const uint4*>(h8 + (size_t)node * C + boff);
        unpk4(v.x, acc); unpk4(v.y, acc + 4); unpk4(v.z, acc + 8); unpk4(v.w, acc + 12);
    }
    const int beg = offs[node], end = beg + cnt[node];
    int p = beg;
    for (; p + 4 <= end; p += 4) {
        int s0 = eidx[p], s1 = eidx[p + 1], s2 = eidx[p + 2], s3 = eidx[p + 3];
        uint4 v0 = *reinterpret_cast<const uint4*>(h8 + (size_t)s0 * C + boff);
        uint4 v1 = *reinterpret_cast<const uint4*>(h8 + (size_t)s1 * C + boff);
        uint4 v2 = *reinterpret_cast<const uint4*>(h8 + (size_t)s2 * C + boff);
        uint4 v3 = *reinterpret_cast<const uint4*>(h8 + (size_t)s3 * C + boff);
        float t[16];
        unpk4(v0.x, t); unpk4(v0.y, t+4); unpk4(v0.z, t+8); unpk4(v0.w, t+12);
        #pragma unroll
        for (int j = 0; j < 16; ++j) acc[j] += t[j];
        unpk4(v1.x, t); unpk4(v1.y, t+4); unpk4(v1.z, t+8); unpk4(v1.w, t+12);
        #pragma unroll
        for (int j = 0; j < 16; ++j) acc[j] += t[j];
        unpk4(v2.x, t); unpk4(v2.y, t+4); unpk4(v2.z, t+8); unpk4(v2.w, t+12);
        #pragma unroll
        for (int j = 0; j < 16; ++j) acc[j] += t[j];
        unpk4(v3.x, t); unpk4(v3.y, t+4); unpk4(v3.z, t+8); unpk4(v3.w, t+12);
        #pragma unroll
        for (int j = 0; j < 16; ++j) acc[j] += t[j];
    }
    for (; p < end; ++p) {
        uint4 v0 = *reinterpret_cast<const uint4*>(h8 + (size_t)eidx[p] * C + boff);
        float t[16];
        unpk4(v0.x, t); unpk4(v0.y, t+4); unpk4(v0.z, t+8); unpk4(v0.w, t+12);
        #pragma unroll
        for (int j = 0; j < 16; ++j) acc[j] += t[j];
    }
    union { unsigned short us[16]; uint4 v[2]; } o;
    #pragma unroll
    for (int j = 0; j < 16; ++j) o.us[j] = f2bf(acc[j]);
    unsigned short* dst = A + (size_t)node * C + lane * 16;
    *reinterpret_cast<uint4*>(dst)     = o.v[0];
    *reinterpret_cast<uint4*>(dst + 8) = o.v[1];
}

// ---------------- fused 2-GEMM MLP via MFMA bf16, 128-row tile ---------------
// OUT_MODE: 0 = f32, 1 = bf16, 2 = fp8 e4m3
template<int K1, int N2, bool RELU_OUT, int OUT_MODE>
__global__ __launch_bounds__(256) void mlp_mfma_k(
    const unsigned short* __restrict__ Ain,
    const unsigned short* __restrict__ WTa,
    const float* __restrict__ ba,
    const unsigned short* __restrict__ WTb,
    const float* __restrict__ bb,
    void* __restrict__ outp, int n_nodes)
{
    constexpr int KS1 = K1 / 32;
    constexpr int NT2 = N2 / 16;
    static_assert(128 * K1 <= 128 * 128, "sA fits sAM");
    static_assert(OUT_MODE != 0 || 128 * N2 * 4 <= 128 * 128 * 2, "f32 stage fits");

    __shared__ __align__(16) unsigned short sAM[128 * 128];  // sA / sMid / out
    __shared__ __align__(16) unsigned short sWa[128 * K1];
    __shared__ __align__(16) unsigned short sWb[N2 * 128];

    const int tid = threadIdx.x;
    const int wave = tid >> 6, lane = tid & 63;
    const int rc = lane & 15;
    const int kg = lane >> 4;
    const int rowBlock = blockIdx.x * 128;

    {   // stage A [128][K1] (guarded rows), swizzled
        constexpr int CPR = K1 / 8;
        #pragma unroll
        for (int f = tid; f < 128 * CPR; f += 256) {
            int r = f / CPR, c = f - r * CPR;
            uint4 v = make_uint4(0u, 0u, 0u, 0u);
            int gr = rowBlock + r;
            if (gr < n_nodes)
                v = *reinterpret_cast<const uint4*>(Ain + (size_t)gr * K1 + c * 8);
            int byte = r * (K1 * 2) + ((c * 16) ^ ((r & 7) << 4));
            *reinterpret_cast<uint4*>((char*)sAM + byte) = v;
        }
    }
    {   // stage WTa [128][K1], swizzled
        constexpr int CPR = K1 / 8;
        #pragma unroll
        for (int f = tid; f < 128 * CPR; f += 256) {
            int r = f / CPR, c = f - r * CPR;
            uint4 v = *reinterpret_cast<const uint4*>(WTa + (size_t)r * K1 + c * 8);
            int byte = r * (K1 * 2) + ((c * 16) ^ ((r & 7) << 4));
            *reinterpret_cast<uint4*>((char*)sWa + byte) = v;
        }
    }
    {   // stage WTb [N2][128], swizzled
        #pragma unroll
        for (int f = tid; f < N2 * 16; f += 256) {
            int r = f / 16, c = f - r * 16;
            uint4 v = *reinterpret_cast<const uint4*>(WTb + (size_t)r * 128 + c * 8);
            int byte = r * 256 + ((c * 16) ^ ((r & 7) << 4));
            *reinterpret_cast<uint4*>((char*)sWb + byte) = v;
        }
    }
    __syncthreads();

    // ---- GEMM1: (128 x K1) @ (K1 x 128) ----
    bf16x8 af[2][KS1];
    #pragma unroll
    for (int rt = 0; rt < 2; ++rt)
        #pragma unroll
        for (int ks = 0; ks < KS1; ++ks) {
            int r = wave * 32 + rt * 16 + rc;
            int byte = r * (K1 * 2) + (((ks * 32 + kg * 8) * 2) ^ ((r & 7) << 4));
            af[rt][ks] = *reinterpret_cast<const bf16x8*>((const char*)sAM + byte);
        }
    __syncthreads();   // all sA reads complete before sMid overwrite

    f32x4 acc1[2][8];
    #pragma unroll
    for (int rt = 0; rt < 2; ++rt)
        #pragma unroll
        for (int n = 0; n < 8; ++n) acc1[rt][n] = (f32x4){0.f, 0.f, 0.f, 0.f};
    #pragma unroll
    for (int n = 0; n < 8; ++n) {
        int c = n * 16 + rc;
        #pragma unroll
        for (int ks = 0; ks < KS1; ++ks) {
            int byte = c * (K1 * 2) + (((ks * 32 + kg * 8) * 2) ^ ((c & 7) << 4));
            bf16x8 bfr = *reinterpret_cast<const bf16x8*>((const char*)sWa + byte);
            #pragma unroll
            for (int rt = 0; rt < 2; ++rt)
                acc1[rt][n] = __builtin_amdgcn_mfma_f32_16x16x32_bf16(
                    af[rt][ks], bfr, acc1[rt][n], 0, 0, 0);
        }
    }
    // epilogue 1: bias + relu -> sMid (= sAM) bf16 [128][128] swizzled
    #pragma unroll
    for (int n = 0; n < 8; ++n) {
        int c = n * 16 + rc;
        float bias = ba[c];
        #pragma unroll
        for (int rt = 0; rt < 2; ++rt)
            #pragma unroll
            for (int i = 0; i < 4; ++i) {
                int r = wave * 32 + rt * 16 + kg * 4 + i;
                float v = fmaxf(acc1[rt][n][i] + bias, 0.f);
                int byte = r * 256 + ((c * 2) ^ ((r & 7) << 4));
                *reinterpret_cast<unsigned short*>((char*)sAM + byte) = f2bf(v);
            }
    }
    __syncthreads();

    // ---- GEMM2: (128 x 128) @ (128 x N2) ----
    bf16x8 mf[2][4];
    #pragma unroll
    for (int rt = 0; rt < 2; ++rt)
        #pragma unroll
        for (int ks = 0; ks < 4; ++ks) {
            int r = wave * 32 + rt * 16 + rc;
            int byte = r * 256 + (((ks * 32 + kg * 8) * 2) ^ ((r & 7) << 4));
            mf[rt][ks] = *reinterpret_cast<const bf16x8*>((const char*)sAM + byte);
        }
    f32x4 acc2[2][NT2];
    #pragma unroll
    for (int rt = 0; rt < 2; ++rt)
        #pragma unroll
        for (int n = 0; n < NT2; ++n) acc2[rt][n] = (f32x4){0.f, 0.f, 0.f, 0.f};
    #pragma unroll
    for (int n = 0; n < NT2; ++n) {
        int c = n * 16 + rc;
        #pragma unroll
        for (int ks = 0; ks < 4; ++ks) {
            int byte = c * 256 + (((ks * 32 + kg * 8) * 2) ^ ((c & 7) << 4));
            bf16x8 bfr = *reinterpret_cast<const bf16x8*>((const char*)sWb + byte);
            #pragma unroll
            for (int rt = 0; rt < 2; ++rt)
                acc2[rt][n] = __builtin_amdgcn_mfma_f32_16x16x32_bf16(
                    mf[rt][ks], bfr, acc2[rt][n], 0, 0, 0);
        }
    }
    __syncthreads();   // all sMid reads done before out-staging overwrite

    // ---- epilogue 2: bias [+relu] -> stage in sAM -> coalesced store ----
    if constexpr (OUT_MODE == 1 || OUT_MODE == 2) {
        #pragma unroll
        for (int n = 0; n < NT2; ++n) {
            int c = n * 16 + rc;
            float bias = bb[c];
            #pragma unroll
            for (int rt = 0; rt < 2; ++rt)
                #pragma unroll
                for (int i = 0; i < 4; ++i) {
                    int r = wave * 32 + rt * 16 + kg * 4 + i;
                    float v = acc2[rt][n][i] + bias;
                    if (RELU_OUT) v = fmaxf(v, 0.f);
                    sAM[r * N2 + c] = f2bf(v);
                }
        }
        __syncthreads();
        if constexpr (OUT_MODE == 1) {
            unsigned short* out = (unsigned short*)outp;
            constexpr int CPR = N2 / 8;
            #pragma unroll
            for (int f = tid; f < 128 * CPR; f += 256) {
                int r = f / CPR, c = f - r * CPR;
                int gr = rowBlock + r;
                if (gr < n_nodes)
                    *reinterpret_cast<uint4*>(out + (size_t)gr * N2 + c * 8) =
                        *reinterpret_cast<const uint4*>(sAM + r * N2 + c * 8);
            }
        } else {   // fp8: convert 8 bf16 -> 8 fp8 per thread-iter, store uint2
            unsigned char* out = (unsigned char*)outp;
            constexpr int GPR = N2 / 8;          // 8-ch granules per row
            #pragma unroll
            for (int f = tid; f < 128 * GPR; f += 256) {
                int r = f / GPR, c8 = f - r * GPR;
                int gr = rowBlock + r;
                if (gr < n_nodes) {
                    uint4 v = *reinterpret_cast<const uint4*>(sAM + r * N2 + c8 * 8);
                    const unsigned short* u = (const unsigned short*)&v;
                    float xx[8];
                    #pragma unroll
                    for (int j = 0; j < 8; ++j) xx[j] = bf2f(u[j]);
                    unsigned int w0 = pk_fp8<false>(xx[0], xx[1], 0u);
                    w0 = pk_fp8<true>(xx[2], xx[3], w0);
                    unsigned int w1 = pk_fp8<false>(xx[4], xx[5], 0u);
                    w1 = pk_fp8<true>(xx[6], xx[7], w1);
                    *reinterpret_cast<uint2*>(out + (size_t)gr * N2 + c8 * 8) =
                        make_uint2(w0, w1);
                }
            }
        }
    } else {
        float* sOut = reinterpret_cast<float*>(sAM);   // [128][N2] f32
        #pragma unroll
        for (int n = 0; n < NT2; ++n) {
            int c = n * 16 + rc;
            float bias = bb[c];
            #pragma unroll
            for (int rt = 0; rt < 2; ++rt)
                #pragma unroll
                for (int i = 0; i < 4; ++i) {
                    int r = wave * 32 + rt * 16 + kg * 4 + i;
                    float v = acc2[rt][n][i] + bias;
                    if (RELU_OUT) v = fmaxf(v, 0.f);
                    sOut[r * N2 + c] = v;
                }
        }
        __syncthreads();
        float* out = (float*)outp;
        constexpr int CPR = N2 / 4;
        #pragma unroll
        for (int f = tid; f < 128 * CPR; f += 256) {
            int r = f / CPR, c = f - r * CPR;
            int gr = rowBlock + r;
            if (gr < n_nodes)
                *reinterpret_cast<float4*>(out + (size_t)gr * N2 + c * 4) =
                    *reinterpret_cast<const float4*>(sOut + r * N2 + c * 4);
        }
    }
}

extern "C" void kernel_launch(void* const* d_in, const int* in_sizes, int n_in,
                              void* d_out, int out_size, void* d_ws, size_t ws_size,
                              hipStream_t stream)
{
    const float* x   = (const float*)d_in[0];
    const int*   ei  = (const int*)d_in[1];
    const float* W1a = (const float*)d_in[2];
    const float* b1a = (const float*)d_in[3];
    const float* W1b = (const float*)d_in[4];
    const float* b1b = (const float*)d_in[5];
    const float* W2a = (const float*)d_in[6];
    const float* b2a = (const float*)d_in[7];
    const float* W2b = (const float*)d_in[8];
    const float* b2b = (const float*)d_in[9];

    const int n_nodes = in_sizes[0] / 64;
    const int n_edges = in_sizes[1] / 2;
    const int* src = ei;
    const int* dst = ei + n_edges;

    char* ws = (char*)d_ws;
    size_t o = 0;
    auto alloc = [&](size_t bytes) -> char* {
        char* p = ws + o;
        o += (bytes + 255) & ~(size_t)255;
        return p;
    };
    unsigned short* A    = (unsigned short*)alloc((size_t)n_nodes * 128 * 2);
    unsigned char*  h8   = (unsigned char*)alloc((size_t)n_nodes * 128);
    unsigned short* xb   = (unsigned short*)alloc((size_t)n_nodes * 64 * 2);
    int* eidx = (int*)alloc((size_t)n_edges * 4);
    unsigned int* tmp = (unsigned int*)alloc((size_t)n_edges * 4);
    int* cnt  = (int*)alloc((size_t)n_nodes * 4);
    int* offs = (int*)alloc((size_t)n_nodes * 4);
    int* cur  = (int*)alloc((size_t)n_nodes * 4);
    int* bsum = (int*)alloc(256 * 4);
    int* gcur = (int*)alloc(NBMX * 4);
    int* bcnt = (int*)alloc((NBMX + 1) * 4);
    int* boffs = (int*)alloc((NBMX + 1) * 4);
    unsigned short* WT1a = (unsigned short*)alloc(64 * 128 * 2);
    unsigned short* WT1b = (unsigned short*)alloc(128 * 128 * 2);
    unsigned short* WT2a = (unsigned short*)alloc(128 * 128 * 2);
    unsigned short* WT2b = (unsigned short*)alloc(128 * 64 * 2);

    const int mlp_grid = (n_nodes + 127) / 128;
    const int egrid = (n_edges + 255) / 256;
    const int nbuck = (n_nodes + CB - 1) / CB;

    // ---- prep (weights + x->bf16) ----
    prep_k<<<192 + (n_nodes * 8 + 255) / 256, 256, 0, stream>>>(
        x, xb, n_nodes * 8, W1a, W1b, W2a, W2b, WT1a, WT1b, WT2a, WT2b);

    // ---- CSR build ----
    if (nbuck <= NBMX && n_nodes < (1 << 20)) {
        hipMemsetAsync(bcnt, 0, (NBMX + 1) * sizeof(int), stream);
        bhist_k<<<128, 256, 0, stream>>>(dst, bcnt, n_edges, nbuck);
        bscan_k<<<1, 256, 0, stream>>>(bcnt, boffs, gcur, nbuck);
        const bool vec4 = ((n_edges & 7) == 0);
        if (vec4)
            bucket_p1_k<true><<<256, 256, 0, stream>>>(src, dst, gcur, tmp, n_edges, nbuck);
        else
            bucket_p1_k<false><<<256, 256, 0, stream>>>(src, dst, gcur, tmp, n_edges, nbuck);
        bucket_csr_k<<<nbuck, 256, 0, stream>>>(tmp, boffs, offs, cnt, eidx, n_nodes);
    } else {
        hipMemsetAsync(cnt, 0, (size_t)n_nodes * sizeof(int), stream);
        hist_k<<<egrid, 256, 0, stream>>>(dst, cnt, n_edges);
        const int nb = (n_nodes + 2047) / 2048;
        scan_block_k<<<nb, 256, 0, stream>>>(cnt, offs, bsum, n_nodes);
        scan_bsum_k<<<1, 256, 0, stream>>>(bsum, nb);
        scan_add_k<<<nb, 256, 0, stream>>>(offs, cur, bsum, n_nodes);
        fill_k<<<egrid, 256, 0, stream>>>(src, dst, cur, eidx, n_edges);
    }

    // ---- layer 1 (h stored fp8) ----
    gather_agg_k<64><<<(n_nodes + 31) / 32, 256, 0, stream>>>(
        xb, offs, cnt, eidx, A, n_nodes);
    mlp_mfma_k<64, 128, true, 2><<<mlp_grid, 256, 0, stream>>>(
        A, WT1a, b1a, WT1b, b1b, h8, n_nodes);

    // ---- layer 2 (fp8 gather) ----
    gather_agg_fp8_k<<<(n_nodes + 31) / 32, 256, 0, stream>>>(
        h8, offs, cnt, eidx, A, n_nodes);
    mlp_mfma_k<128, 64, false, 0><<<mlp_grid, 256, 0, stream>>>(
        A, WT2a, b2a, WT2b, b2b, d_out, n_nodes);
}

// Round 14
// 175.314 us; speedup vs baseline: 1.2433x; 1.0092x over previous
//
#include <hip/hip_runtime.h>
#include <hip/hip_bf16.h>

// GIN 2-layer, bf16 feature pipeline + MFMA MLPs, fp8 inter-layer h (r13).
// r14: bcnt zeroing folded into prep_k (no fill kernel in the graph);
// bhist grid 128 -> 256.

#define CB   512        // nodes per coarse bucket
#define NBMX 256        // max buckets (bucket path requires nbuck <= 256)
#define CAP  48         // LDS staged entries per bucket (p1)
#define FL   16         // flush granularity (16 x u32 = 64 B line)

typedef short  bf16x8 __attribute__((ext_vector_type(8)));
typedef float  f32x4  __attribute__((ext_vector_type(4)));
typedef float  f32x2  __attribute__((ext_vector_type(2)));

__device__ inline float bf2f(unsigned short u) {
    unsigned int t = ((unsigned int)u) << 16;
    return __builtin_bit_cast(float, t);
}
__device__ inline unsigned short f2bf(float f) {   // round-to-nearest-even
    unsigned int u = __builtin_bit_cast(unsigned int, f);
    u += 0x7fffu + ((u >> 16) & 1u);
    return (unsigned short)(u >> 16);
}
// fp8 e4m3 (OCP on gfx950) pack/unpack via HW converts.
template<bool HI>
__device__ inline unsigned int pk_fp8(float a, float b, unsigned int old) {
    return (unsigned int)__builtin_amdgcn_cvt_pk_fp8_f32(a, b, (int)old, HI);
}
__device__ inline void unpk4(unsigned int w, float* o) {
    f32x2 lo = __builtin_amdgcn_cvt_pk_f32_fp8(w, false);
    f32x2 hi = __builtin_amdgcn_cvt_pk_f32_fp8(w, true);
    o[0] = lo.x; o[1] = lo.y; o[2] = hi.x; o[3] = hi.y;
}

// --- prep: weights transpose->bf16 | x->bf16 | bcnt zero, one launch --------
__global__ __launch_bounds__(256) void prep_k(
    const float* __restrict__ x, unsigned short* __restrict__ xb, int n8,
    const float* __restrict__ W1a, const float* __restrict__ W1b,
    const float* __restrict__ W2a, const float* __restrict__ W2b,
    unsigned short* __restrict__ T1a, unsigned short* __restrict__ T1b,
    unsigned short* __restrict__ T2a, unsigned short* __restrict__ T2b,
    int* __restrict__ bcnt)
{
    int b = blockIdx.x;
    const int tid = threadIdx.x;
    if (b < 192) {                       // WT[n][k] = bf16(W[k][n])
        int idx = b * 256 + tid;
        const float* W; unsigned short* T; int K, N;
        if (idx < 8192)        { W = W1a; T = T1a; K = 64;  N = 128; }
        else if (idx < 24576)  { idx -= 8192;  W = W1b; T = T1b; K = 128; N = 128; }
        else if (idx < 40960)  { idx -= 24576; W = W2a; T = T2a; K = 128; N = 128; }
        else if (idx < 49152)  { idx -= 40960; W = W2b; T = T2b; K = 128; N = 64; }
        else return;
        int n = idx / K, k = idx - n * K;
        T[idx] = f2bf(W[(size_t)k * N + n]);
    } else {
        int b2 = b - 192;
        const int xb_blocks = (n8 + 255) / 256;
        if (b2 < xb_blocks) {            // x -> bf16
            int i = b2 * 256 + tid;
            if (i >= n8) return;
            const float4* p = reinterpret_cast<const float4*>(x + (size_t)i * 8);
            float4 a = p[0], c = p[1];
            union { unsigned short us[8]; uint4 v; } o;
            o.us[0] = f2bf(a.x); o.us[1] = f2bf(a.y); o.us[2] = f2bf(a.z); o.us[3] = f2bf(a.w);
            o.us[4] = f2bf(c.x); o.us[5] = f2bf(c.y); o.us[6] = f2bf(c.z); o.us[7] = f2bf(c.w);
            *reinterpret_cast<uint4*>(xb + (size_t)i * 8) = o.v;
        } else {                         // zero bcnt (runs before bhist launch)
            for (int i = tid; i < NBMX + 1; i += 256) bcnt[i] = 0;
        }
    }
}

// ---------------- per-bucket histogram (LDS, few global atomics) -------------
__global__ __launch_bounds__(256) void bhist_k(
    const int* __restrict__ dst, int* __restrict__ bcnt, int n_edges, int nbuck)
{
    __shared__ int lh[NBMX];
    const int tid = threadIdx.x;
    for (int b = tid; b < nbuck; b += 256) lh[b] = 0;
    __syncthreads();
    const int e4 = n_edges >> 2;
    const int stride = gridDim.x * 256;
    for (int i4 = blockIdx.x * 256 + tid; i4 < e4; i4 += stride) {
        int4 dv = reinterpret_cast<const int4*>(dst)[i4];
        atomicAdd(&lh[dv.x / CB], 1);
        atomicAdd(&lh[dv.y / CB], 1);
        atomicAdd(&lh[dv.z / CB], 1);
        atomicAdd(&lh[dv.w / CB], 1);
    }
    if (blockIdx.x == 0 && tid < (n_edges & 3))
        atomicAdd(&lh[dst[e4 * 4 + tid] / CB], 1);
    __syncthreads();
    for (int b = tid; b < nbuck; b += 256) {
        int v = lh[b];
        if (v) atomicAdd(&bcnt[b], v);
    }
}

// ---------------- bucket scan (1 block): boffs + gcur ----------------
__global__ __launch_bounds__(256) void bscan_k(
    const int* __restrict__ bcnt, int* __restrict__ boffs,
    int* __restrict__ gcur, int nbuck)
{
    __shared__ int s[256];
    const int tid = threadIdx.x;
    int v = (tid < nbuck) ? bcnt[tid] : 0;
    s[tid] = v; __syncthreads();
    #pragma unroll
    for (int d = 1; d < 256; d <<= 1) {
        int t = (tid >= d) ? s[tid - d] : 0;
        __syncthreads();
        s[tid] += t;
        __syncthreads();
    }
    if (tid < nbuck) {
        int excl = s[tid] - v;
        boffs[tid] = excl;
        gcur[tid] = excl;
        if (tid == nbuck - 1) boffs[nbuck] = s[tid];
    }
}

// ---------------- pass 1: LDS-staged binning, 8 edges/thread/iter (r11) ------
template<bool VEC4>
__global__ __launch_bounds__(256) void bucket_p1_k(
    const int* __restrict__ src, const int* __restrict__ dst,
    int* __restrict__ gcur, unsigned int* __restrict__ tmp,
    int n_edges, int nb)
{
    __shared__ unsigned int stage[NBMX][CAP];
    __shared__ int scnt[NBMX];
    const int tid = threadIdx.x;
    for (int b = tid; b < nb; b += 256) scnt[b] = 0;
    __syncthreads();

    const int e8total = n_edges >> 3;
    const int stride = gridDim.x * 256;
    const int iters = (e8total + stride - 1) / stride;

    for (int it = 0; it < iters; ++it) {
        int i8 = it * stride + blockIdx.x * 256 + tid;
        if (i8 < e8total) {
            int s8[8], d8[8];
            if constexpr (VEC4) {
                int4 sv0 = reinterpret_cast<const int4*>(src)[i8 * 2];
                int4 sv1 = reinterpret_cast<const int4*>(src)[i8 * 2 + 1];
                int4 dv0 = reinterpret_cast<const int4*>(dst)[i8 * 2];
                int4 dv1 = reinterpret_cast<const int4*>(dst)[i8 * 2 + 1];
                s8[0]=sv0.x; s8[1]=sv0.y; s8[2]=sv0.z; s8[3]=sv0.w;
                s8[4]=sv1.x; s8[5]=sv1.y; s8[6]=sv1.z; s8[7]=sv1.w;
                d8[0]=dv0.x; d8[1]=dv0.y; d8[2]=dv0.z; d8[3]=dv0.w;
                d8[4]=dv1.x; d8[5]=dv1.y; d8[6]=dv1.z; d8[7]=dv1.w;
            } else {
                #pragma unroll
                for (int j = 0; j < 8; ++j) { s8[j]=src[i8*8+j]; d8[j]=dst[i8*8+j]; }
            }
            #pragma unroll
            for (int j = 0; j < 8; ++j) {
                int dd = d8[j];
                int b = dd / CB;
                unsigned int entry = (unsigned int)s8[j] | ((unsigned int)(dd - b * CB) << 20);
                int slot = atomicAdd(&scnt[b], 1);
                if (slot < CAP) stage[b][slot] = entry;
                else { int p = atomicAdd(&gcur[b], 1); tmp[p] = entry; }
            }
        }
        __syncthreads();
        if (tid < nb) {
            int m = scnt[tid]; if (m > CAP) m = CAP;
            while (m >= FL) {
                int base = atomicAdd(&gcur[tid], FL);
                #pragma unroll
                for (int q = 0; q < FL; ++q)
                    tmp[base + q] = stage[tid][m - FL + q];
                m -= FL;
            }
            scnt[tid] = m;
        }
        __syncthreads();
    }
    if (tid < nb) {
        int m = scnt[tid]; if (m > CAP) m = CAP;
        if (m > 0) {
            int base = atomicAdd(&gcur[tid], m);
            for (int q = 0; q < m; ++q) tmp[base + q] = stage[tid][q];
        }
    }
    if (blockIdx.x == 0 && tid < (n_edges & 7)) {
        int e = e8total * 8 + tid;
        int dd = dst[e];
        int b = dd / CB;
        unsigned int entry = (unsigned int)src[e] | ((unsigned int)(dd - b * CB) << 20);
        int p = atomicAdd(&gcur[b], 1);
        tmp[p] = entry;
    }
}

// ---------------- pass 2: bucket-local count + scan + scatter (proven) -------
__global__ __launch_bounds__(256) void bucket_csr_k(
    const unsigned int* __restrict__ tmp, const int* __restrict__ boffs,
    int* __restrict__ offs, int* __restrict__ cnt, int* __restrict__ eidx,
    int n_nodes)
{
    __shared__ int lcnt[CB];
    __shared__ int lcur[CB];
    __shared__ int ssum[256];
    const int b = blockIdx.x;
    const int tid = threadIdx.x;
    const int node0 = b * CB;
    const int nn = min(CB, n_nodes - node0);
    const int lo = boffs[b], hi = boffs[b + 1];

    for (int i = tid; i < CB; i += 256) lcnt[i] = 0;
    __syncthreads();
    for (int i = lo + tid; i < hi; i += 256)
        atomicAdd(&lcnt[tmp[i] >> 20], 1);
    __syncthreads();

    int a0 = lcnt[tid * 2], a1 = lcnt[tid * 2 + 1];
    int tsum = a0 + a1;
    ssum[tid] = tsum; __syncthreads();
    #pragma unroll
    for (int d = 1; d < 256; d <<= 1) {
        int t = (tid >= d) ? ssum[tid - d] : 0;
        __syncthreads();
        ssum[tid] += t;
        __syncthreads();
    }
    int run = ssum[tid] - tsum;

    lcur[tid * 2]     = run;
    lcur[tid * 2 + 1] = run + a0;
    int g0 = node0 + tid * 2;
    if (tid * 2 < nn)     { offs[g0]     = lo + run;      cnt[g0]     = a0; }
    if (tid * 2 + 1 < nn) { offs[g0 + 1] = lo + run + a0; cnt[g0 + 1] = a1; }
    __syncthreads();

    for (int i = lo + tid; i < hi; i += 256) {
        unsigned int v = tmp[i];
        int p = atomicAdd(&lcur[v >> 20], 1);
        eidx[lo + p] = (int)(v & 0xFFFFFu);
    }
}

// ---------------- fallback pipeline (nbuck > NBMX) ----------------
__global__ __launch_bounds__(256) void hist_k(
    const int* __restrict__ dst, int* __restrict__ cnt, int n_edges)
{
    int e = blockIdx.x * 256 + threadIdx.x;
    if (e < n_edges) atomicAdd(&cnt[dst[e]], 1);
}

__global__ __launch_bounds__(256) void scan_block_k(
    const int* __restrict__ cnt, int* __restrict__ offs, int* __restrict__ bsum, int n)
{
    __shared__ int s[256];
    const int tid = threadIdx.x;
    const int base = blockIdx.x * 2048 + tid * 8;
    int v[8]; int tsum = 0;
    #pragma unroll
    for (int j = 0; j < 8; ++j) {
        int idx = base + j;
        v[j] = (idx < n) ? cnt[idx] : 0;
        tsum += v[j];
    }
    s[tid] = tsum; __syncthreads();
    #pragma unroll
    for (int d = 1; d < 256; d <<= 1) {
        int t = (tid >= d) ? s[tid - d] : 0;
        __syncthreads();
        s[tid] += t;
        __syncthreads();
    }
    int run = s[tid] - tsum;
    #pragma unroll
    for (int j = 0; j < 8; ++j) {
        int idx = base + j;
        if (idx < n) offs[idx] = run;
        run += v[j];
    }
    if (tid == 255) bsum[blockIdx.x] = s[255];
}

__global__ __launch_bounds__(256) void scan_bsum_k(int* __restrict__ bsum, int nb)
{
    __shared__ int s[256];
    const int tid = threadIdx.x;
    int v = (tid < nb) ? bsum[tid] : 0;
    s[tid] = v; __syncthreads();
    #pragma unroll
    for (int d = 1; d < 256; d <<= 1) {
        int t = (tid >= d) ? s[tid - d] : 0;
        __syncthreads();
        s[tid] += t;
        __syncthreads();
    }
    if (tid < nb) bsum[tid] = s[tid] - v;
}

__global__ __launch_bounds__(256) void scan_add_k(
    int* __restrict__ offs, int* __restrict__ cur, const int* __restrict__ bsum, int n)
{
    const int b = bsum[blockIdx.x];
    const int base = blockIdx.x * 2048 + threadIdx.x * 8;
    #pragma unroll
    for (int j = 0; j < 8; ++j) {
        int idx = base + j;
        if (idx < n) { int o = offs[idx] + b; offs[idx] = o; cur[idx] = o; }
    }
}

__global__ __launch_bounds__(256) void fill_k(
    const int* __restrict__ src, const int* __restrict__ dst,
    int* __restrict__ cur, int* __restrict__ eidx, int n_edges)
{
    int e = blockIdx.x * 256 + threadIdx.x;
    if (e < n_edges) {
        int p = atomicAdd(&cur[dst[e]], 1);
        eidx[p] = src[e];
    }
}

// ---------------- gather (bf16, layer 1): A = self + sum(nbrs) ---------------
template<int C>
__global__ __launch_bounds__(256) void gather_agg_k(
    const unsigned short* __restrict__ h, const int* __restrict__ offs,
    const int* __restrict__ cnt, const int* __restrict__ eidx,
    unsigned short* __restrict__ A, int n_nodes)
{
    constexpr int TPN = C / 8;
    constexpr int NPB = 256 / TPN;
    const int node = blockIdx.x * NPB + threadIdx.x / TPN;
    const int lane = threadIdx.x % TPN;
    if (node >= n_nodes) return;
    const size_t coff = (size_t)lane * 8;

    float acc[8];
    {
        uint4 v = *reinterpret_cast<const uint4*>(h + (size_t)node * C + coff);
        const unsigned short* u = (const unsigned short*)&v;
        #pragma unroll
        for (int j = 0; j < 8; ++j) acc[j] = bf2f(u[j]);
    }
    const int beg = offs[node], end = beg + cnt[node];
    int p = beg;
    for (; p + 4 <= end; p += 4) {
        int s0 = eidx[p], s1 = eidx[p + 1], s2 = eidx[p + 2], s3 = eidx[p + 3];
        uint4 v0 = *reinterpret_cast<const uint4*>(h + (size_t)s0 * C + coff);
        uint4 v1 = *reinterpret_cast<const uint4*>(h + (size_t)s1 * C + coff);
        uint4 v2 = *reinterpret_cast<const uint4*>(h + (size_t)s2 * C + coff);
        uint4 v3 = *reinterpret_cast<const uint4*>(h + (size_t)s3 * C + coff);
        const unsigned short* u0 = (const unsigned short*)&v0;
        const unsigned short* u1 = (const unsigned short*)&v1;
        const unsigned short* u2 = (const unsigned short*)&v2;
        const unsigned short* u3 = (const unsigned short*)&v3;
        #pragma unroll
        for (int j = 0; j < 8; ++j)
            acc[j] += (bf2f(u0[j]) + bf2f(u1[j])) + (bf2f(u2[j]) + bf2f(u3[j]));
    }
    if (p + 2 <= end) {
        int s0 = eidx[p], s1 = eidx[p + 1];
        uint4 v0 = *reinterpret_cast<const uint4*>(h + (size_t)s0 * C + coff);
        uint4 v1 = *reinterpret_cast<const uint4*>(h + (size_t)s1 * C + coff);
        const unsigned short* u0 = (const unsigned short*)&v0;
        const unsigned short* u1 = (const unsigned short*)&v1;
        #pragma unroll
        for (int j = 0; j < 8; ++j) acc[j] += bf2f(u0[j]) + bf2f(u1[j]);
        p += 2;
    }
    if (p < end) {
        uint4 v0 = *reinterpret_cast<const uint4*>(h + (size_t)eidx[p] * C + coff);
        const unsigned short* u0 = (const unsigned short*)&v0;
        #pragma unroll
        for (int j = 0; j < 8; ++j) acc[j] += bf2f(u0[j]);
    }
    union { unsigned short us[8]; uint4 v; } o;
    #pragma unroll
    for (int j = 0; j < 8; ++j) o.us[j] = f2bf(acc[j]);
    *reinterpret_cast<uint4*>(A + (size_t)node * C + coff) = o.v;
}

// ---------------- gather (fp8, layer 2): A = self + sum(nbrs), bf16 out ------
__global__ __launch_bounds__(256) void gather_agg_fp8_k(
    const unsigned char* __restrict__ h8, const int* __restrict__ offs,
    const int* __restrict__ cnt, const int* __restrict__ eidx,
    unsigned short* __restrict__ A, int n_nodes)
{
    constexpr int C = 128;
    constexpr int TPN = 8;
    constexpr int NPB = 256 / TPN;   // 32 nodes/block
    const int node = blockIdx.x * NPB + threadIdx.x / TPN;
    const int lane = threadIdx.x % TPN;
    if (node >= n_nodes) return;
    const size_t boff = (size_t)lane * 16;

    float acc[16];
    {   // self
        uint4 v = *reinterpret_cast<const uint4*>(h8 + (size_t)node * C + boff);
        unpk4(v.x, acc); unpk4(v.y, acc + 4); unpk4(v.z, acc + 8); unpk4(v.w, acc + 12);
    }
    const int beg = offs[node], end = beg + cnt[node];
    int p = beg;
    for (; p + 4 <= end; p += 4) {
        int s0 = eidx[p], s1 = eidx[p + 1], s2 = eidx[p + 2], s3 = eidx[p + 3];
        uint4 v0 = *reinterpret_cast<const uint4*>(h8 + (size_t)s0 * C + boff);
        uint4 v1 = *reinterpret_cast<const uint4*>(h8 + (size_t)s1 * C + boff);
        uint4 v2 = *reinterpret_cast<const uint4*>(h8 + (size_t)s2 * C + boff);
        uint4 v3 = *reinterpret_cast<const uint4*>(h8 + (size_t)s3 * C + boff);
        float t[16];
        unpk4(v0.x, t); unpk4(v0.y, t+4); unpk4(v0.z, t+8); unpk4(v0.w, t+12);
        #pragma unroll
        for (int j = 0; j < 16; ++j) acc[j] += t[j];
        unpk4(v1.x, t); unpk4(v1.y, t+4); unpk4(v1.z, t+8); unpk4(v1.w, t+12);
        #pragma unroll
        for (int j = 0; j < 16; ++j) acc[j] += t[j];
        unpk4(v2.x, t); unpk4(v2.y, t+4); unpk4(v2.z, t+8); unpk4(v2.w, t+12);
        #pragma unroll
        for (int j = 0; j < 16; ++j) acc[j] += t[j];
        unpk4(v3.x, t); unpk4(v3.y, t+4); unpk4(v3.z, t+8); unpk4(v3.w, t+12);
        #pragma unroll
        for (int j = 0; j < 16; ++j) acc[j] += t[j];
    }
    for (; p < end; ++p) {
        uint4 v0 = *reinterpret_cast<const uint4*>(h8 + (size_t)eidx[p] * C + boff);
        float t[16];
        unpk4(v0.x, t); unpk4(v0.y, t+4); unpk4(v0.z, t+8); unpk4(v0.w, t+12);
        #pragma unroll
        for (int j = 0; j < 16; ++j) acc[j] += t[j];
    }
    union { unsigned short us[16]; uint4 v[2]; } o;
    #pragma unroll
    for (int j = 0; j < 16; ++j) o.us[j] = f2bf(acc[j]);
    unsigned short* dst = A + (size_t)node * C + lane * 16;
    *reinterpret_cast<uint4*>(dst)     = o.v[0];
    *reinterpret_cast<uint4*>(dst + 8) = o.v[1];
}

// ---------------- fused 2-GEMM MLP via MFMA bf16, 128-row tile ---------------
// OUT_MODE: 0 = f32, 1 = bf16, 2 = fp8 e4m3
template<int K1, int N2, bool RELU_OUT, int OUT_MODE>
__global__ __launch_bounds__(256) void mlp_mfma_k(
    const unsigned short* __restrict__ Ain,
    const unsigned short* __restrict__ WTa,
    const float* __restrict__ ba,
    const unsigned short* __restrict__ WTb,
    const float* __restrict__ bb,
    void* __restrict__ outp, int n_nodes)
{
    constexpr int KS1 = K1 / 32;
    constexpr int NT2 = N2 / 16;
    static_assert(128 * K1 <= 128 * 128, "sA fits sAM");
    static_assert(OUT_MODE != 0 || 128 * N2 * 4 <= 128 * 128 * 2, "f32 stage fits");

    __shared__ __align__(16) unsigned short sAM[128 * 128];  // sA / sMid / out
    __shared__ __align__(16) unsigned short sWa[128 * K1];
    __shared__ __align__(16) unsigned short sWb[N2 * 128];

    const int tid = threadIdx.x;
    const int wave = tid >> 6, lane = tid & 63;
    const int rc = lane & 15;
    const int kg = lane >> 4;
    const int rowBlock = blockIdx.x * 128;

    {   // stage A [128][K1] (guarded rows), swizzled
        constexpr int CPR = K1 / 8;
        #pragma unroll
        for (int f = tid; f < 128 * CPR; f += 256) {
            int r = f / CPR, c = f - r * CPR;
            uint4 v = make_uint4(0u, 0u, 0u, 0u);
            int gr = rowBlock + r;
            if (gr < n_nodes)
                v = *reinterpret_cast<const uint4*>(Ain + (size_t)gr * K1 + c * 8);
            int byte = r * (K1 * 2) + ((c * 16) ^ ((r & 7) << 4));
            *reinterpret_cast<uint4*>((char*)sAM + byte) = v;
        }
    }
    {   // stage WTa [128][K1], swizzled
        constexpr int CPR = K1 / 8;
        #pragma unroll
        for (int f = tid; f < 128 * CPR; f += 256) {
            int r = f / CPR, c = f - r * CPR;
            uint4 v = *reinterpret_cast<const uint4*>(WTa + (size_t)r * K1 + c * 8);
            int byte = r * (K1 * 2) + ((c * 16) ^ ((r & 7) << 4));
            *reinterpret_cast<uint4*>((char*)sWa + byte) = v;
        }
    }
    {   // stage WTb [N2][128], swizzled
        #pragma unroll
        for (int f = tid; f < N2 * 16; f += 256) {
            int r = f / 16, c = f - r * 16;
            uint4 v = *reinterpret_cast<const uint4*>(WTb + (size_t)r * 128 + c * 8);
            int byte = r * 256 + ((c * 16) ^ ((r & 7) << 4));
            *reinterpret_cast<uint4*>((char*)sWb + byte) = v;
        }
    }
    __syncthreads();

    // ---- GEMM1: (128 x K1) @ (K1 x 128) ----
    bf16x8 af[2][KS1];
    #pragma unroll
    for (int rt = 0; rt < 2; ++rt)
        #pragma unroll
        for (int ks = 0; ks < KS1; ++ks) {
            int r = wave * 32 + rt * 16 + rc;
            int byte = r * (K1 * 2) + (((ks * 32 + kg * 8) * 2) ^ ((r & 7) << 4));
            af[rt][ks] = *reinterpret_cast<const bf16x8*>((const char*)sAM + byte);
        }
    __syncthreads();   // all sA reads complete before sMid overwrite

    f32x4 acc1[2][8];
    #pragma unroll
    for (int rt = 0; rt < 2; ++rt)
        #pragma unroll
        for (int n = 0; n < 8; ++n) acc1[rt][n] = (f32x4){0.f, 0.f, 0.f, 0.f};
    #pragma unroll
    for (int n = 0; n < 8; ++n) {
        int c = n * 16 + rc;
        #pragma unroll
        for (int ks = 0; ks < KS1; ++ks) {
            int byte = c * (K1 * 2) + (((ks * 32 + kg * 8) * 2) ^ ((c & 7) << 4));
            bf16x8 bfr = *reinterpret_cast<const bf16x8*>((const char*)sWa + byte);
            #pragma unroll
            for (int rt = 0; rt < 2; ++rt)
                acc1[rt][n] = __builtin_amdgcn_mfma_f32_16x16x32_bf16(
                    af[rt][ks], bfr, acc1[rt][n], 0, 0, 0);
        }
    }
    // epilogue 1: bias + relu -> sMid (= sAM) bf16 [128][128] swizzled
    #pragma unroll
    for (int n = 0; n < 8; ++n) {
        int c = n * 16 + rc;
        float bias = ba[c];
        #pragma unroll
        for (int rt = 0; rt < 2; ++rt)
            #pragma unroll
            for (int i = 0; i < 4; ++i) {
                int r = wave * 32 + rt * 16 + kg * 4 + i;
                float v = fmaxf(acc1[rt][n][i] + bias, 0.f);
                int byte = r * 256 + ((c * 2) ^ ((r & 7) << 4));
                *reinterpret_cast<unsigned short*>((char*)sAM + byte) = f2bf(v);
            }
    }
    __syncthreads();

    // ---- GEMM2: (128 x 128) @ (128 x N2) ----
    bf16x8 mf[2][4];
    #pragma unroll
    for (int rt = 0; rt < 2; ++rt)
        #pragma unroll
        for (int ks = 0; ks < 4; ++ks) {
            int r = wave * 32 + rt * 16 + rc;
            int byte = r * 256 + (((ks * 32 + kg * 8) * 2) ^ ((r & 7) << 4));
            mf[rt][ks] = *reinterpret_cast<const bf16x8*>((const char*)sAM + byte);
        }
    f32x4 acc2[2][NT2];
    #pragma unroll
    for (int rt = 0; rt < 2; ++rt)
        #pragma unroll
        for (int n = 0; n < NT2; ++n) acc2[rt][n] = (f32x4){0.f, 0.f, 0.f, 0.f};
    #pragma unroll
    for (int n = 0; n < NT2; ++n) {
        int c = n * 16 + rc;
        #pragma unroll
        for (int ks = 0; ks < 4; ++ks) {
            int byte = c * 256 + (((ks * 32 + kg * 8) * 2) ^ ((c & 7) << 4));
            bf16x8 bfr = *reinterpret_cast<const bf16x8*>((const char*)sWb + byte);
            #pragma unroll
            for (int rt = 0; rt < 2; ++rt)
                acc2[rt][n] = __builtin_amdgcn_mfma_f32_16x16x32_bf16(
                    mf[rt][ks], bfr, acc2[rt][n], 0, 0, 0);
        }
    }
    __syncthreads();   // all sMid reads done before out-staging overwrite

    // ---- epilogue 2: bias [+relu] -> stage in sAM -> coalesced store ----
    if constexpr (OUT_MODE == 1 || OUT_MODE == 2) {
        #pragma unroll
        for (int n = 0; n < NT2; ++n) {
            int c = n * 16 + rc;
            float bias = bb[c];
            #pragma unroll
            for (int rt = 0; rt < 2; ++rt)
                #pragma unroll
                for (int i = 0; i < 4; ++i) {
                    int r = wave * 32 + rt * 16 + kg * 4 + i;
                    float v = acc2[rt][n][i] + bias;
                    if (RELU_OUT) v = fmaxf(v, 0.f);
                    sAM[r * N2 + c] = f2bf(v);
                }
        }
        __syncthreads();
        if constexpr (OUT_MODE == 1) {
            unsigned short* out = (unsigned short*)outp;
            constexpr int CPR = N2 / 8;
            #pragma unroll
            for (int f = tid; f < 128 * CPR; f += 256) {
                int r = f / CPR, c = f - r * CPR;
                int gr = rowBlock + r;
                if (gr < n_nodes)
                    *reinterpret_cast<uint4*>(out + (size_t)gr * N2 + c * 8) =
                        *reinterpret_cast<const uint4*>(sAM + r * N2 + c * 8);
            }
        } else {   // fp8: convert 8 bf16 -> 8 fp8 per thread-iter, store uint2
            unsigned char* out = (unsigned char*)outp;
            constexpr int GPR = N2 / 8;
            #pragma unroll
            for (int f = tid; f < 128 * GPR; f += 256) {
                int r = f / GPR, c8 = f - r * GPR;
                int gr = rowBlock + r;
                if (gr < n_nodes) {
                    uint4 v = *reinterpret_cast<const uint4*>(sAM + r * N2 + c8 * 8);
                    const unsigned short* u = (const unsigned short*)&v;
                    float xx[8];
                    #pragma unroll
                    for (int j = 0; j < 8; ++j) xx[j] = bf2f(u[j]);
                    unsigned int w0 = pk_fp8<false>(xx[0], xx[1], 0u);
                    w0 = pk_fp8<true>(xx[2], xx[3], w0);
                    unsigned int w1 = pk_fp8<false>(xx[4], xx[5], 0u);
                    w1 = pk_fp8<true>(xx[6], xx[7], w1);
                    *reinterpret_cast<uint2*>(out + (size_t)gr * N2 + c8 * 8) =
                        make_uint2(w0, w1);
                }
            }
        }
    } else {
        float* sOut = reinterpret_cast<float*>(sAM);   // [128][N2] f32
        #pragma unroll
        for (int n = 0; n < NT2; ++n) {
            int c = n * 16 + rc;
            float bias = bb[c];
            #pragma unroll
            for (int rt = 0; rt < 2; ++rt)
                #pragma unroll
                for (int i = 0; i < 4; ++i) {
                    int r = wave * 32 + rt * 16 + kg * 4 + i;
                    float v = acc2[rt][n][i] + bias;
                    if (RELU_OUT) v = fmaxf(v, 0.f);
                    sOut[r * N2 + c] = v;
                }
        }
        __syncthreads();
        float* out = (float*)outp;
        constexpr int CPR = N2 / 4;
        #pragma unroll
        for (int f = tid; f < 128 * CPR; f += 256) {
            int r = f / CPR, c = f - r * CPR;
            int gr = rowBlock + r;
            if (gr < n_nodes)
                *reinterpret_cast<float4*>(out + (size_t)gr * N2 + c * 4) =
                    *reinterpret_cast<const float4*>(sOut + r * N2 + c * 4);
        }
    }
}

extern "C" void kernel_launch(void* const* d_in, const int* in_sizes, int n_in,
                              void* d_out, int out_size, void* d_ws, size_t ws_size,
                              hipStream_t stream)
{
    const float* x   = (const float*)d_in[0];
    const int*   ei  = (const int*)d_in[1];
    const float* W1a = (const float*)d_in[2];
    const float* b1a = (const float*)d_in[3];
    const float* W1b = (const float*)d_in[4];
    const float* b1b = (const float*)d_in[5];
    const float* W2a = (const float*)d_in[6];
    const float* b2a = (const float*)d_in[7];
    const float* W2b = (const float*)d_in[8];
    const float* b2b = (const float*)d_in[9];

    const int n_nodes = in_sizes[0] / 64;
    const int n_edges = in_sizes[1] / 2;
    const int* src = ei;
    const int* dst = ei + n_edges;

    char* ws = (char*)d_ws;
    size_t o = 0;
    auto alloc = [&](size_t bytes) -> char* {
        char* p = ws + o;
        o += (bytes + 255) & ~(size_t)255;
        return p;
    };
    unsigned short* A    = (unsigned short*)alloc((size_t)n_nodes * 128 * 2);
    unsigned char*  h8   = (unsigned char*)alloc((size_t)n_nodes * 128);
    unsigned short* xb   = (unsigned short*)alloc((size_t)n_nodes * 64 * 2);
    int* eidx = (int*)alloc((size_t)n_edges * 4);
    unsigned int* tmp = (unsigned int*)alloc((size_t)n_edges * 4);
    int* cnt  = (int*)alloc((size_t)n_nodes * 4);
    int* offs = (int*)alloc((size_t)n_nodes * 4);
    int* cur  = (int*)alloc((size_t)n_nodes * 4);
    int* bsum = (int*)alloc(256 * 4);
    int* gcur = (int*)alloc(NBMX * 4);
    int* bcnt = (int*)alloc((NBMX + 1) * 4);
    int* boffs = (int*)alloc((NBMX + 1) * 4);
    unsigned short* WT1a = (unsigned short*)alloc(64 * 128 * 2);
    unsigned short* WT1b = (unsigned short*)alloc(128 * 128 * 2);
    unsigned short* WT2a = (unsigned short*)alloc(128 * 128 * 2);
    unsigned short* WT2b = (unsigned short*)alloc(128 * 64 * 2);

    const int mlp_grid = (n_nodes + 127) / 128;
    const int egrid = (n_edges + 255) / 256;
    const int nbuck = (n_nodes + CB - 1) / CB;

    // ---- prep (weights + x->bf16 + bcnt zero; zero done before bhist) ----
    const int n8 = n_nodes * 8;
    const int xb_blocks = (n8 + 255) / 256;
    prep_k<<<192 + xb_blocks + 1, 256, 0, stream>>>(
        x, xb, n8, W1a, W1b, W2a, W2b, WT1a, WT1b, WT2a, WT2b, bcnt);

    // ---- CSR build ----
    if (nbuck <= NBMX && n_nodes < (1 << 20)) {
        bhist_k<<<256, 256, 0, stream>>>(dst, bcnt, n_edges, nbuck);
        bscan_k<<<1, 256, 0, stream>>>(bcnt, boffs, gcur, nbuck);
        const bool vec4 = ((n_edges & 7) == 0);
        if (vec4)
            bucket_p1_k<true><<<256, 256, 0, stream>>>(src, dst, gcur, tmp, n_edges, nbuck);
        else
            bucket_p1_k<false><<<256, 256, 0, stream>>>(src, dst, gcur, tmp, n_edges, nbuck);
        bucket_csr_k<<<nbuck, 256, 0, stream>>>(tmp, boffs, offs, cnt, eidx, n_nodes);
    } else {
        hipMemsetAsync(cnt, 0, (size_t)n_nodes * sizeof(int), stream);
        hist_k<<<egrid, 256, 0, stream>>>(dst, cnt, n_edges);
        const int nb = (n_nodes + 2047) / 2048;
        scan_block_k<<<nb, 256, 0, stream>>>(cnt, offs, bsum, n_nodes);
        scan_bsum_k<<<1, 256, 0, stream>>>(bsum, nb);
        scan_add_k<<<nb, 256, 0, stream>>>(offs, cur, bsum, n_nodes);
        fill_k<<<egrid, 256, 0, stream>>>(src, dst, cur, eidx, n_edges);
    }

    // ---- layer 1 (h stored fp8) ----
    gather_agg_k<64><<<(n_nodes + 31) / 32, 256, 0, stream>>>(
        xb, offs, cnt, eidx, A, n_nodes);
    mlp_mfma_k<64, 128, true, 2><<<mlp_grid, 256, 0, stream>>>(
        A, WT1a, b1a, WT1b, b1b, h8, n_nodes);

    // ---- layer 2 (fp8 gather) ----
    gather_agg_fp8_k<<<(n_nodes + 31) / 32, 256, 0, stream>>>(
        h8, offs, cnt, eidx, A, n_nodes);
    mlp_mfma_k<128, 64, false, 0><<<mlp_grid, 256, 0, stream>>>(
        A, WT2a, b2a, WT2b, b2b, d_out, n_nodes);
}